// Round 2
// baseline (1401.908 us; speedup 1.0000x reference)
//
#include <hip/hip_runtime.h>
#include <hip/hip_bf16.h>

#define DIV_UP(a,b) (((a)+(b)-1)/(b))

typedef __bf16 bf16x8 __attribute__((ext_vector_type(8)));
typedef float  f32x4  __attribute__((ext_vector_type(4)));

// ---- runtime dtype detector: bf16 data -> low 16b half of each word has a sane
// bf16 exponent; f32 data -> low half is mantissa garbage. flag=1 means bf16.
__global__ __launch_bounds__(256) void detect_dtype(const unsigned int* __restrict__ x,
                                                    int* __restrict__ flag) {
  __shared__ int cnt_s;
  if (threadIdx.x == 0) cnt_s = 0;
  __syncthreads();
  unsigned w = x[threadIdx.x];
  unsigned lo_exp = (w >> 7) & 0xFF;
  if (lo_exp >= 100 && lo_exp <= 140) atomicAdd(&cnt_s, 1);
  __syncthreads();
  if (threadIdx.x == 0) flag[0] = (cnt_s >= 128) ? 1 : 0;
}

// y[n,64] = x[n,K] @ w[64,K]^T via v_mfma_f32_16x16x32_bf16 (round-5 proven).
// xmode/wmode: 0 = f32 pointer, 1 = bf16 pointer, 2 = dual (use *flagp).
template<int K>
__global__ __launch_bounds__(256) void gemm_mfma(
    const void* __restrict__ x, int xmode,
    const void* __restrict__ w, int woff, int wmode,
    const int* __restrict__ flagp, __hip_bfloat16* __restrict__ out, int n) {
  constexpr int KP = K + 8;
  __shared__ __bf16 xs[64 * KP];
  const bool xb = (xmode == 2) ? (*flagp != 0) : (xmode == 1);
  const bool wb = (wmode == 2) ? (*flagp != 0) : (wmode == 1);
  const int t = threadIdx.x;
  const int wv = t >> 6;
  const int L = t & 63;
  const int m = L & 15, q = L >> 4;
  const int row0 = blockIdx.x * 64;
  const int col = wv * 16 + m;

  bf16x8 bfr[K / 32];
  if (wb) {
    const __bf16* wh = (const __bf16*)w + woff;
#pragma unroll
    for (int ks = 0; ks < K / 32; ++ks)
      bfr[ks] = *(const bf16x8*)&wh[col * K + ks * 32 + q * 8];
  } else {
    const float* wf = (const float*)w + woff;
#pragma unroll
    for (int ks = 0; ks < K / 32; ++ks) {
      bf16x8 b;
#pragma unroll
      for (int j = 0; j < 8; ++j) b[j] = (__bf16)wf[col * K + ks * 32 + q * 8 + j];
      bfr[ks] = b;
    }
  }

  constexpr int CH = K / 8;
  if (xb) {
    const __bf16* xh = (const __bf16*)x;
    for (int idx = t; idx < 64 * CH; idx += 256) {
      int r = idx / CH, c = idx % CH;
      int gr = row0 + r; gr = (gr < n) ? gr : (n - 1);
      *(bf16x8*)&xs[r * KP + c * 8] = *(const bf16x8*)&xh[(size_t)gr * K + c * 8];
    }
  } else {
    const float* xf = (const float*)x;
    for (int idx = t; idx < 64 * CH; idx += 256) {
      int r = idx / CH, c = idx % CH;
      int gr = row0 + r; gr = (gr < n) ? gr : (n - 1);
      const float* src = &xf[(size_t)gr * K + c * 8];
      bf16x8 v;
#pragma unroll
      for (int j = 0; j < 8; ++j) v[j] = (__bf16)src[j];
      *(bf16x8*)&xs[r * KP + c * 8] = v;
    }
  }
  __syncthreads();

  f32x4 acc[4] = {};
#pragma unroll
  for (int ks = 0; ks < K / 32; ++ks) {
#pragma unroll
    for (int rt = 0; rt < 4; ++rt) {
      bf16x8 a = *(const bf16x8*)&xs[(rt * 16 + m) * KP + ks * 32 + q * 8];
      acc[rt] = __builtin_amdgcn_mfma_f32_16x16x32_bf16(a, bfr[ks], acc[rt], 0, 0, 0);
    }
  }

#pragma unroll
  for (int rt = 0; rt < 4; ++rt) {
#pragma unroll
    for (int i = 0; i < 4; ++i) {
      int gr = row0 + rt * 16 + q * 4 + i;
      if (gr < n) out[(size_t)gr * 64 + col] = __float2bfloat16(acc[rt][i]);
    }
  }
}

// ======== fused per-(layer, dst-type): lin_r MFMA + edge-parallel multi-relation
// CSR gather (LDS-atomic accumulation) + epilogue (relu->h / l2norm->out).
// Block = 256 (4 waves) per 16 dst rows. Edge spans split evenly across waves;
// monotone row tracking; per-row-run register accumulation -> 1 ds_add per run. ========
template<int K, int MODE>  // MODE 0: relu->bf16; MODE 1: l2norm->flag dtype
__global__ __launch_bounds__(256) void fused_agg(
    const void* __restrict__ xdst, int xmode,
    const int* __restrict__ flagp,
    const __hip_bfloat16* __restrict__ wrsum,  // [64][K] bf16 (merged lin_r)
    const float* __restrict__ bias,            // [64] (merged)
    const int* __restrict__ col,               // shared CSR col array
    const int* __restrict__ rp0, const __hip_bfloat16* __restrict__ y0,
    const int* __restrict__ rp1, const __hip_bfloat16* __restrict__ y1,
    const int* __restrict__ rp2, const __hip_bfloat16* __restrict__ y2,
    int nrel, float invR,
    void* __restrict__ outp, size_t obase, int n) {
  __shared__ float dbuf[16][68];
  __shared__ int rpl_s[3][17];   // rowptr[row0..row0+16] per relation (clamped at n)
  const bool xb = (xmode == 2) ? (*flagp != 0) : (xmode == 1);
  const int t = threadIdx.x;
  const int wv = t >> 6, L = t & 63;
  const int m = L & 15, q = L >> 4;
  const int row0 = blockIdx.x * 16;
  const int colc = wv * 16 + m;

  // --- cooperative rowptr load (overlaps with MFMA latency; one sync covers both) ---
  if (t < 51) {
    int j = t / 17, k = t - j * 17;
    if (j < nrel) {
      const int* rp = (j == 0) ? rp0 : (j == 1) ? rp1 : rp2;
      int gi = row0 + k; gi = (gi < n) ? gi : n;   // rows >= n -> zero-length spans
      rpl_s[j][k] = rp[gi];
    }
  }

  // --- lin_r MFMA: B fragments = this wave's 16 cols of Wr_sum ---
  const __bf16* wh = (const __bf16*)wrsum;
  bf16x8 bfr[K / 32];
#pragma unroll
  for (int ks = 0; ks < K / 32; ++ks)
    bfr[ks] = *(const bf16x8*)&wh[colc * K + ks * 32 + q * 8];

  // A fragments: row (row0+m) of x_dst
  int ar = row0 + m; ar = (ar < n) ? ar : (n - 1);
  f32x4 acc = {};
  if (xb) {
    const __bf16* xp = (const __bf16*)xdst;
#pragma unroll
    for (int ks = 0; ks < K / 32; ++ks) {
      bf16x8 a = *(const bf16x8*)&xp[(size_t)ar * K + ks * 32 + q * 8];
      acc = __builtin_amdgcn_mfma_f32_16x16x32_bf16(a, bfr[ks], acc, 0, 0, 0);
    }
  } else {
    const float* xp = (const float*)xdst;
#pragma unroll
    for (int ks = 0; ks < K / 32; ++ks) {
      bf16x8 a;
#pragma unroll
      for (int j = 0; j < 8; ++j) a[j] = (__bf16)xp[(size_t)ar * K + ks * 32 + q * 8 + j];
      acc = __builtin_amdgcn_mfma_f32_16x16x32_bf16(a, bfr[ks], acc, 0, 0, 0);
    }
  }
  float bc = bias[colc];
#pragma unroll
  for (int i = 0; i < 4; ++i) dbuf[q * 4 + i][colc] = acc[i] + bc;  // D row = q*4+i
  __syncthreads();

  // --- edge-parallel gather: each wave takes a contiguous quarter of each
  // relation's edge span; per-row-run register accumulation; one LDS atomic per run.
  const __hip_bfloat16* ys[3] = {y0, y1, y2};
#pragma unroll 1
  for (int j = 0; j < nrel; ++j) {
    const __hip_bfloat16* yy = ys[j];
    const int* rp = &rpl_s[j][0];
    int sb = rp[0], se = rp[16];
    int span = se - sb;
    if (span <= 0) continue;
    int per = (span + 3) >> 2;
    int e = sb + wv * per;
    int myend = e + per; myend = (myend < se) ? myend : se;
    if (e >= myend) continue;
    // locate starting row (last row whose start <= e)
    int r = 0;
#pragma unroll
    for (int k = 1; k < 16; ++k) r += (e >= rp[k]);
    int nxt = rp[r + 1];
    while (e < myend) {
      while (e >= nxt) { ++r; nxt = rp[r + 1]; }   // skips empty rows
      int rbeg = rp[r];
      float idg = 1.0f / (float)(nxt - rbeg);      // full per-(row,rel) degree
      int stop = (nxt < myend) ? nxt : myend;
      float g = 0.0f;
      for (; e + 8 <= stop; e += 8) {
        int c0 = col[e],     c1 = col[e + 1], c2 = col[e + 2], c3 = col[e + 3];
        int c4 = col[e + 4], c5 = col[e + 5], c6 = col[e + 6], c7 = col[e + 7];
        float v0 = __bfloat162float(yy[(size_t)c0 * 64 + L]);
        float v1 = __bfloat162float(yy[(size_t)c1 * 64 + L]);
        float v2 = __bfloat162float(yy[(size_t)c2 * 64 + L]);
        float v3 = __bfloat162float(yy[(size_t)c3 * 64 + L]);
        float v4 = __bfloat162float(yy[(size_t)c4 * 64 + L]);
        float v5 = __bfloat162float(yy[(size_t)c5 * 64 + L]);
        float v6 = __bfloat162float(yy[(size_t)c6 * 64 + L]);
        float v7 = __bfloat162float(yy[(size_t)c7 * 64 + L]);
        g += ((v0 + v1) + (v2 + v3)) + ((v4 + v5) + (v6 + v7));
      }
      for (; e + 4 <= stop; e += 4) {
        int c0 = col[e], c1 = col[e + 1], c2 = col[e + 2], c3 = col[e + 3];
        float v0 = __bfloat162float(yy[(size_t)c0 * 64 + L]);
        float v1 = __bfloat162float(yy[(size_t)c1 * 64 + L]);
        float v2 = __bfloat162float(yy[(size_t)c2 * 64 + L]);
        float v3 = __bfloat162float(yy[(size_t)c3 * 64 + L]);
        g += (v0 + v1) + (v2 + v3);
      }
      for (; e < stop; ++e) g += __bfloat162float(yy[(size_t)col[e] * 64 + L]);
      atomicAdd(&dbuf[r][L], g * idg);             // banks (r*68+L)%32: conflict-free
    }
  }
  __syncthreads();

  // --- epilogue ---
#pragma unroll 1
  for (int rr = 0; rr < 4; ++rr) {
    int gr = row0 + wv * 4 + rr;  // wave-uniform
    if (gr >= n) continue;
    float s = dbuf[wv * 4 + rr][L] * invR;
    if (MODE == 0) {
      ((__hip_bfloat16*)outp)[obase + (size_t)gr * 64 + L] =
          __float2bfloat16(fmaxf(s, 0.0f));
    } else {
      float ss = s * s;
#pragma unroll
      for (int o = 32; o > 0; o >>= 1) ss += __shfl_xor(ss, o, 64);
      float sc = 1.0f / fmaxf(sqrtf(ss), 1e-12f);
      float r = s * sc;
      size_t idx = obase + (size_t)gr * 64 + L;
      if (*flagp) ((__hip_bfloat16*)outp)[idx] = __float2bfloat16(r);
      else        ((float*)outp)[idx] = r;
    }
  }
}

// ======== CSR build (round-4 proven) ========
__global__ __launch_bounds__(256) void count_int(const int* __restrict__ ed,
                                                 int* __restrict__ deg, int E) {
  int i = blockIdx.x * 256 + threadIdx.x;
  if (i < E) atomicAdd(&deg[ed[i]], 1);
}

__global__ __launch_bounds__(256) void scan1(const int* __restrict__ deg,
    int* __restrict__ outp, int* __restrict__ part, int n) {
  __shared__ int tmp[256];
  int gid = blockIdx.x * 256 + threadIdx.x;
  int v = (gid < n) ? deg[gid] : 0;
  tmp[threadIdx.x] = v;
  __syncthreads();
  for (int off = 1; off < 256; off <<= 1) {
    int t = (threadIdx.x >= off) ? tmp[threadIdx.x - off] : 0;
    __syncthreads();
    tmp[threadIdx.x] += t;
    __syncthreads();
  }
  if (gid < n) outp[gid] = tmp[threadIdx.x] - v;  // exclusive
  if (threadIdx.x == 255) part[blockIdx.x] = tmp[255];
}

__global__ __launch_bounds__(256) void scan2(int* __restrict__ part, int P,
                                             int* __restrict__ totalout) {
  __shared__ int tmp[256];
  __shared__ int carry;
  if (threadIdx.x == 0) carry = 0;
  __syncthreads();
  for (int base0 = 0; base0 < P; base0 += 256) {
    int i = base0 + threadIdx.x;
    int v = (i < P) ? part[i] : 0;
    tmp[threadIdx.x] = v;
    __syncthreads();
    for (int off = 1; off < 256; off <<= 1) {
      int t = (threadIdx.x >= off) ? tmp[threadIdx.x - off] : 0;
      __syncthreads();
      tmp[threadIdx.x] += t;
      __syncthreads();
    }
    if (i < P) part[i] = tmp[threadIdx.x] - v + carry;
    __syncthreads();
    if (threadIdx.x == 0) carry += tmp[255];
    __syncthreads();
  }
  if (threadIdx.x == 0) *totalout = carry;
}

__global__ __launch_bounds__(256) void scan3(int* __restrict__ outp,
    const int* __restrict__ part, int n) {
  int gid = blockIdx.x * 256 + threadIdx.x;
  if (gid < n) outp[gid] += part[blockIdx.x];
}

__global__ __launch_bounds__(256) void copy_int(const int* __restrict__ src,
                                                int* __restrict__ dst, int n) {
  int i = blockIdx.x * 256 + threadIdx.x;
  if (i < n) dst[i] = src[i];
}

__global__ __launch_bounds__(256) void fill_csr(const int* __restrict__ es,
    const int* __restrict__ ed, int* __restrict__ cursor, int* __restrict__ col, int E) {
  int i = blockIdx.x * 256 + threadIdx.x;
  if (i < E) {
    int pos = atomicAdd(&cursor[ed[i]], 1);
    col[pos] = es[i];
  }
}

// wout(bf16) = W[o0] + W[o1] (+ W[o2]); bout(f32) similarly; offsets in elements
__global__ __launch_bounds__(256) void wsum_kernel(
    const void* __restrict__ W, int o0, int o1, int o2,
    const void* __restrict__ B, int p0, int p1, int p2,
    const int* __restrict__ flagp, __hip_bfloat16* __restrict__ wout,
    float* __restrict__ bout, int wsz) {
  const bool bf = (*flagp != 0);
  int i = blockIdx.x * 256 + threadIdx.x;
  float s = 0.0f, sb = 0.0f;
  if (bf) {
    const __hip_bfloat16* Wp = (const __hip_bfloat16*)W;
    const __hip_bfloat16* Bp = (const __hip_bfloat16*)B;
    if (i < wsz) {
      s = __bfloat162float(Wp[o0 + i]) + __bfloat162float(Wp[o1 + i]);
      if (o2 >= 0) s += __bfloat162float(Wp[o2 + i]);
    }
    if (i < 64) {
      sb = __bfloat162float(Bp[p0 + i]) + __bfloat162float(Bp[p1 + i]);
      if (p2 >= 0) sb += __bfloat162float(Bp[p2 + i]);
    }
  } else {
    const float* Wp = (const float*)W;
    const float* Bp = (const float*)B;
    if (i < wsz) {
      s = Wp[o0 + i] + Wp[o1 + i];
      if (o2 >= 0) s += Wp[o2 + i];
    }
    if (i < 64) {
      sb = Bp[p0 + i] + Bp[p1 + i];
      if (p2 >= 0) sb += Bp[p2 + i];
    }
  }
  if (i < wsz) wout[i] = __float2bfloat16(s);
  if (i < 64) bout[i] = sb;
}

extern "C" void kernel_launch(void* const* d_in, const int* in_sizes, int n_in,
                              void* d_out, int out_size, void* d_ws, size_t ws_size,
                              hipStream_t stream) {
  const int NC = 100000, NM = 50000, ND = 25000;
  const int nn[3] = {NC, NM, ND};
  const size_t toff[3] = {0, (size_t)NC * 64, (size_t)(NC + NM) * 64};
  const void* X[3] = {d_in[0], d_in[1], d_in[2]};
  const int* eptr[8]; int E[8];
  for (int r = 0; r < 8; ++r) { eptr[r] = (const int*)d_in[3 + r]; E[r] = in_sizes[3 + r] / 2; }
  const void* Wls[3] = {d_in[11], d_in[14], d_in[17]};
  const void* Wrs[3] = {d_in[12], d_in[15], d_in[18]};
  const void* Bbs[3] = {d_in[13], d_in[16], d_in[19]};

  // relation r: 0:c->m 1:m->d 2:c->d 3:m->c 4:d->m 5:d->c 6:c->c 7:m->m
  const int src_t[8] = {0, 1, 0, 1, 2, 2, 0, 1};
  const int dst_t[8] = {1, 2, 2, 0, 1, 0, 0, 1};
  // relations per dst type (3rd used only in layer 3 for T=0,1)
  const int relT[3][3] = {{3, 5, 6}, {0, 4, 7}, {1, 2, -1}};

  int coff[8]; int cntN = 0;
  for (int r = 0; r < 8; ++r) { coff[r] = cntN; cntN += nn[dst_t[r]]; }
  int Etot = 0; for (int r = 0; r < 8; ++r) Etot += E[r];

  // ---- workspace carve (~60 MB; round-5 proved ws_size >= ~73 MB) ----
  char* base = (char*)d_ws;
  int* flag = (int*)base; base += 16;
  __hip_bfloat16* wr[3];
  for (int t = 0; t < 3; ++t) { wr[t] = (__hip_bfloat16*)base; base += 64 * 128 * 2; }
  float* bs[3]; for (int t = 0; t < 3; ++t) { bs[t] = (float*)base; base += 64 * 4; }
  __hip_bfloat16* y = (__hip_bfloat16*)base; base += (size_t)175000 * 64 * 2;  // max rows/phase
  int* degcur = (int*)base; base += (size_t)cntN * 4;
  int* rowptr = (int*)base; base += (size_t)(cntN + 1) * 4;
  int* part = (int*)base; base += (size_t)(DIV_UP(cntN, 256) + 1) * 4;
  int* col = (int*)base; base += (size_t)Etot * 4;
  __hip_bfloat16* h2 = (__hip_bfloat16*)base; base += (size_t)175000 * 64 * 2;
  __hip_bfloat16* h1 = (__hip_bfloat16*)d_out;  // prefix of d_out; dead before layer-3 writes
  (void)n_in; (void)out_size; (void)ws_size;

  detect_dtype<<<1, 256, 0, stream>>>((const unsigned int*)d_in[0], flag);

  // ---- CSR build (edges fixed; shared by all layers) ----
  hipMemsetAsync(degcur, 0, (size_t)cntN * sizeof(int), stream);
  for (int r = 0; r < 8; ++r)
    count_int<<<DIV_UP(E[r], 256), 256, 0, stream>>>(eptr[r] + E[r], degcur + coff[r], E[r]);
  int nb = DIV_UP(cntN, 256);
  scan1<<<nb, 256, 0, stream>>>(degcur, rowptr, part, cntN);
  scan2<<<1, 256, 0, stream>>>(part, nb, rowptr + cntN);
  scan3<<<nb, 256, 0, stream>>>(rowptr, part, cntN);
  copy_int<<<nb, 256, 0, stream>>>(rowptr, degcur, cntN);  // degcur -> cursor
  for (int r = 0; r < 8; ++r)
    fill_csr<<<DIV_UP(E[r], 256), 256, 0, stream>>>(eptr[r], eptr[r] + E[r],
                                                    degcur + coff[r], col, E[r]);

  for (int layer = 0; layer < 3; ++layer) {
    const void* Wl = Wls[layer];
    const void* Wr = Wrs[layer];
    const void* Bb = Bbs[layer];
    const int K = (layer == 0) ? 128 : 64;
    const int wsz = 64 * K;
    const __hip_bfloat16* hin = (layer == 1) ? h1 : h2;  // layer 0 uses X

    for (int T = 0; T < 3; ++T) {
      const int nrel = (layer == 2 && T < 2) ? 3 : 2;
      const int r0 = relT[T][0], r1 = relT[T][1];
      const int r2 = (nrel == 3) ? relT[T][2] : -1;
      wsum_kernel<<<DIV_UP(wsz, 256), 256, 0, stream>>>(
          Wr, r0 * wsz, r1 * wsz, (r2 >= 0) ? r2 * wsz : -1,
          Bb, r0 * 64, r1 * 64, (r2 >= 0) ? r2 * 64 : -1,
          flag, wr[T], bs[T], wsz);
      // y GEMMs for this dst type's relations
      size_t yoffs[3] = {0, 0, 0};
      size_t yoff = 0;
      for (int j = 0; j < nrel; ++j) {
        int r = relT[T][j], st = src_t[r];
        yoffs[j] = yoff;
        if (layer == 0)
          gemm_mfma<128><<<DIV_UP(nn[st], 64), 256, 0, stream>>>(
              X[st], 2, Wl, r * wsz, 2, flag, y + yoff, nn[st]);
        else
          gemm_mfma<64><<<DIV_UP(nn[st], 64), 256, 0, stream>>>(
              hin + toff[st], 1, Wl, r * wsz, 2, flag, y + yoff, nn[st]);
        yoff += (size_t)nn[st] * 64;
      }
      // fused lin_r + gather + epilogue
      const int* rp0 = rowptr + coff[r0];
      const int* rp1 = rowptr + coff[r1];
      const int* rp2 = (r2 >= 0) ? rowptr + coff[r2] : rp0;
      const __hip_bfloat16* y0 = y + yoffs[0];
      const __hip_bfloat16* y1 = y + yoffs[1];
      const __hip_bfloat16* y2 = (r2 >= 0) ? y + yoffs[2] : y0;
      int grid = DIV_UP(nn[T], 16);
      if (layer == 0) {
        fused_agg<128, 0><<<grid, 256, 0, stream>>>(
            X[T], 2, flag, wr[T], bs[T], col, rp0, y0, rp1, y1, rp2, y2,
            nrel, 0.5f, h1, toff[T], nn[T]);
      } else if (layer == 1) {
        fused_agg<64, 0><<<grid, 256, 0, stream>>>(
            h1 + toff[T], 1, flag, wr[T], bs[T], col, rp0, y0, rp1, y1, rp2, y2,
            nrel, 0.5f, h2, toff[T], nn[T]);
      } else {
        float invR = (T < 2) ? (1.0f / 3.0f) : 0.5f;
        fused_agg<64, 1><<<grid, 256, 0, stream>>>(
            h2 + toff[T], 1, flag, wr[T], bs[T], col, rp0, y0, rp1, y1, rp2, y2,
            nrel, invR, d_out, toff[T], nn[T]);
      }
    }
  }
}

// Round 3
// 1117.862 us; speedup vs baseline: 1.2541x; 1.2541x over previous
//
#include <hip/hip_runtime.h>
#include <hip/hip_bf16.h>

#define DIV_UP(a,b) (((a)+(b)-1)/(b))

typedef __bf16 bf16x8 __attribute__((ext_vector_type(8)));
typedef float  f32x4  __attribute__((ext_vector_type(4)));

// ---- runtime dtype detector: bf16 data -> low 16b half of each word has a sane
// bf16 exponent; f32 data -> low half is mantissa garbage. flag=1 means bf16.
__global__ __launch_bounds__(256) void detect_dtype(const unsigned int* __restrict__ x,
                                                    int* __restrict__ flag) {
  __shared__ int cnt_s;
  if (threadIdx.x == 0) cnt_s = 0;
  __syncthreads();
  unsigned w = x[threadIdx.x];
  unsigned lo_exp = (w >> 7) & 0xFF;
  if (lo_exp >= 100 && lo_exp <= 140) atomicAdd(&cnt_s, 1);
  __syncthreads();
  if (threadIdx.x == 0) flag[0] = (cnt_s >= 128) ? 1 : 0;
}

// y[n,64] = x[n,K] @ w[64,K]^T via v_mfma_f32_16x16x32_bf16 (round-5 proven).
// xmode/wmode: 0 = f32 pointer, 1 = bf16 pointer, 2 = dual (use *flagp).
template<int K>
__global__ __launch_bounds__(256) void gemm_mfma(
    const void* __restrict__ x, int xmode,
    const void* __restrict__ w, int woff, int wmode,
    const int* __restrict__ flagp, __hip_bfloat16* __restrict__ out, int n) {
  constexpr int KP = K + 8;
  __shared__ __bf16 xs[64 * KP];
  const bool xb = (xmode == 2) ? (*flagp != 0) : (xmode == 1);
  const bool wb = (wmode == 2) ? (*flagp != 0) : (wmode == 1);
  const int t = threadIdx.x;
  const int wv = t >> 6;
  const int L = t & 63;
  const int m = L & 15, q = L >> 4;
  const int row0 = blockIdx.x * 64;
  const int col = wv * 16 + m;

  bf16x8 bfr[K / 32];
  if (wb) {
    const __bf16* wh = (const __bf16*)w + woff;
#pragma unroll
    for (int ks = 0; ks < K / 32; ++ks)
      bfr[ks] = *(const bf16x8*)&wh[col * K + ks * 32 + q * 8];
  } else {
    const float* wf = (const float*)w + woff;
#pragma unroll
    for (int ks = 0; ks < K / 32; ++ks) {
      bf16x8 b;
#pragma unroll
      for (int j = 0; j < 8; ++j) b[j] = (__bf16)wf[col * K + ks * 32 + q * 8 + j];
      bfr[ks] = b;
    }
  }

  constexpr int CH = K / 8;
  if (xb) {
    const __bf16* xh = (const __bf16*)x;
    for (int idx = t; idx < 64 * CH; idx += 256) {
      int r = idx / CH, c = idx % CH;
      int gr = row0 + r; gr = (gr < n) ? gr : (n - 1);
      *(bf16x8*)&xs[r * KP + c * 8] = *(const bf16x8*)&xh[(size_t)gr * K + c * 8];
    }
  } else {
    const float* xf = (const float*)x;
    for (int idx = t; idx < 64 * CH; idx += 256) {
      int r = idx / CH, c = idx % CH;
      int gr = row0 + r; gr = (gr < n) ? gr : (n - 1);
      const float* src = &xf[(size_t)gr * K + c * 8];
      bf16x8 v;
#pragma unroll
      for (int j = 0; j < 8; ++j) v[j] = (__bf16)src[j];
      *(bf16x8*)&xs[r * KP + c * 8] = v;
    }
  }
  __syncthreads();

  f32x4 acc[4] = {};
#pragma unroll
  for (int ks = 0; ks < K / 32; ++ks) {
#pragma unroll
    for (int rt = 0; rt < 4; ++rt) {
      bf16x8 a = *(const bf16x8*)&xs[(rt * 16 + m) * KP + ks * 32 + q * 8];
      acc[rt] = __builtin_amdgcn_mfma_f32_16x16x32_bf16(a, bfr[ks], acc[rt], 0, 0, 0);
    }
  }

#pragma unroll
  for (int rt = 0; rt < 4; ++rt) {
#pragma unroll
    for (int i = 0; i < 4; ++i) {
      int gr = row0 + rt * 16 + q * 4 + i;
      if (gr < n) out[(size_t)gr * 64 + col] = __float2bfloat16(acc[rt][i]);
    }
  }
}

// ======== fused per-(layer, dst-type): lin_r MFMA + row-per-wave multi-relation
// CSR gather + epilogue (relu->h / l2norm->out). Block = 256 (4 waves) per 16 dst
// rows; wave wv owns rows wv*4..wv*4+3 (round-0 proven structure).
// New this round: (1) cooperative rowptr->LDS prefetch (kills 12 serial broadcast
// stalls/wave); (2) relation-interleaved masked-uniform 4-edge batches: all NREL
// relations' col loads issue together, then all y loads (up to 12 lines in
// flight), then masked accumulate. No data-dependent branches; all guards are
// wave-uniform. ========
template<int K, int MODE, int NREL>  // MODE 0: relu->bf16; MODE 1: l2norm->flag dtype
__global__ __launch_bounds__(256) void fused_agg(
    const void* __restrict__ xdst, int xmode,
    const int* __restrict__ flagp,
    const __hip_bfloat16* __restrict__ wrsum,  // [64][K] bf16 (merged lin_r)
    const float* __restrict__ bias,            // [64] (merged)
    const int* __restrict__ col,               // shared CSR col array
    const int* __restrict__ rp0, const __hip_bfloat16* __restrict__ y0,
    const int* __restrict__ rp1, const __hip_bfloat16* __restrict__ y1,
    const int* __restrict__ rp2, const __hip_bfloat16* __restrict__ y2,
    float invR,
    void* __restrict__ outp, size_t obase, int n) {
  __shared__ float dbuf[16][68];
  __shared__ int rpl_s[NREL][17];   // rowptr[row0..row0+16] per relation
  const bool xb = (xmode == 2) ? (*flagp != 0) : (xmode == 1);
  const int t = threadIdx.x;
  const int wv = t >> 6, L = t & 63;
  const int m = L & 15, q = L >> 4;
  const int row0 = blockIdx.x * 16;
  const int colc = wv * 16 + m;

  // --- cooperative rowptr load (overlaps MFMA latency; existing sync covers it) ---
  if (t < NREL * 17) {
    int j = t / 17, k = t - j * 17;
    const int* rp = (j == 0) ? rp0 : (j == 1) ? rp1 : rp2;
    int gi = row0 + k; gi = (gi < n) ? gi : n;   // rows >= n -> zero-length spans
    rpl_s[j][k] = rp[gi];
  }

  // --- lin_r MFMA: B fragments = this wave's 16 cols of Wr_sum ---
  const __bf16* wh = (const __bf16*)wrsum;
  bf16x8 bfr[K / 32];
#pragma unroll
  for (int ks = 0; ks < K / 32; ++ks)
    bfr[ks] = *(const bf16x8*)&wh[colc * K + ks * 32 + q * 8];

  // A fragments: row (row0+m) of x_dst
  int ar = row0 + m; ar = (ar < n) ? ar : (n - 1);
  f32x4 acc = {};
  if (xb) {
    const __bf16* xp = (const __bf16*)xdst;
#pragma unroll
    for (int ks = 0; ks < K / 32; ++ks) {
      bf16x8 a = *(const bf16x8*)&xp[(size_t)ar * K + ks * 32 + q * 8];
      acc = __builtin_amdgcn_mfma_f32_16x16x32_bf16(a, bfr[ks], acc, 0, 0, 0);
    }
  } else {
    const float* xp = (const float*)xdst;
#pragma unroll
    for (int ks = 0; ks < K / 32; ++ks) {
      bf16x8 a;
#pragma unroll
      for (int j = 0; j < 8; ++j) a[j] = (__bf16)xp[(size_t)ar * K + ks * 32 + q * 8 + j];
      acc = __builtin_amdgcn_mfma_f32_16x16x32_bf16(a, bfr[ks], acc, 0, 0, 0);
    }
  }
  float bc = bias[colc];
#pragma unroll
  for (int i = 0; i < 4; ++i) dbuf[q * 4 + i][colc] = acc[i] + bc;  // D row = q*4+i
  __syncthreads();

  const __hip_bfloat16* ys[3] = {y0, y1, y2};
#pragma unroll 1
  for (int rr = 0; rr < 4; ++rr) {
    const int lr = wv * 4 + rr;       // wave-uniform local row
    const int gr = row0 + lr;
    if (gr >= n) continue;
    float s = dbuf[lr][L];

    // per-relation stream state (compile-time unrolled -> registers)
    int ptr[NREL], rem[NREL];
    float gg[NREL], idg[NREL];
    int nb = 0;
#pragma unroll
    for (int j = 0; j < NREL; ++j) {
      int b0 = rpl_s[j][lr], e0 = rpl_s[j][lr + 1];
      int d = e0 - b0;
      ptr[j] = b0; rem[j] = d; gg[j] = 0.0f;
      idg[j] = (d > 0) ? (1.0f / (float)d) : 0.0f;
      int nbj = (d + 3) >> 2;
      nb = (nbj > nb) ? nbj : nb;
    }

#pragma unroll 1
    for (int b = 0; b < nb; ++b) {
      // phase 1: col-index loads for every active relation (independent)
      int cidx[NREL][4];
#pragma unroll
      for (int j = 0; j < NREL; ++j) {
        if (rem[j] > 0) {
          int last = rem[j] - 1;
#pragma unroll
          for (int k = 0; k < 4; ++k) {
            int o = (k < last) ? k : last;          // clamp: stay in-bounds
            cidx[j][k] = col[ptr[j] + o];
          }
        }
      }
      // phase 2: y-row loads for every active relation (up to 12 lines in flight)
      float v[NREL][4];
#pragma unroll
      for (int j = 0; j < NREL; ++j) {
        if (rem[j] > 0) {
#pragma unroll
          for (int k = 0; k < 4; ++k)
            v[j][k] = __bfloat162float(ys[j][(size_t)cidx[j][k] * 64 + L]);
        }
      }
      // phase 3: masked accumulate + advance
#pragma unroll
      for (int j = 0; j < NREL; ++j) {
        if (rem[j] > 0) {
          int rj = rem[j];
#pragma unroll
          for (int k = 0; k < 4; ++k)
            gg[j] += (k < rj) ? v[j][k] : 0.0f;
          ptr[j] += 4; rem[j] -= 4;
        }
      }
    }

#pragma unroll
    for (int j = 0; j < NREL; ++j) s += gg[j] * idg[j];
    s *= invR;

    if (MODE == 0) {
      ((__hip_bfloat16*)outp)[obase + (size_t)gr * 64 + L] =
          __float2bfloat16(fmaxf(s, 0.0f));
    } else {
      float ss = s * s;
#pragma unroll
      for (int o = 32; o > 0; o >>= 1) ss += __shfl_xor(ss, o, 64);
      float sc = 1.0f / fmaxf(sqrtf(ss), 1e-12f);
      float r = s * sc;
      size_t idx = obase + (size_t)gr * 64 + L;
      if (*flagp) ((__hip_bfloat16*)outp)[idx] = __float2bfloat16(r);
      else        ((float*)outp)[idx] = r;
    }
  }
}

// ======== CSR build (round-4 proven) ========
__global__ __launch_bounds__(256) void count_int(const int* __restrict__ ed,
                                                 int* __restrict__ deg, int E) {
  int i = blockIdx.x * 256 + threadIdx.x;
  if (i < E) atomicAdd(&deg[ed[i]], 1);
}

__global__ __launch_bounds__(256) void scan1(const int* __restrict__ deg,
    int* __restrict__ outp, int* __restrict__ part, int n) {
  __shared__ int tmp[256];
  int gid = blockIdx.x * 256 + threadIdx.x;
  int v = (gid < n) ? deg[gid] : 0;
  tmp[threadIdx.x] = v;
  __syncthreads();
  for (int off = 1; off < 256; off <<= 1) {
    int t = (threadIdx.x >= off) ? tmp[threadIdx.x - off] : 0;
    __syncthreads();
    tmp[threadIdx.x] += t;
    __syncthreads();
  }
  if (gid < n) outp[gid] = tmp[threadIdx.x] - v;  // exclusive
  if (threadIdx.x == 255) part[blockIdx.x] = tmp[255];
}

__global__ __launch_bounds__(256) void scan2(int* __restrict__ part, int P,
                                             int* __restrict__ totalout) {
  __shared__ int tmp[256];
  __shared__ int carry;
  if (threadIdx.x == 0) carry = 0;
  __syncthreads();
  for (int base0 = 0; base0 < P; base0 += 256) {
    int i = base0 + threadIdx.x;
    int v = (i < P) ? part[i] : 0;
    tmp[threadIdx.x] = v;
    __syncthreads();
    for (int off = 1; off < 256; off <<= 1) {
      int t = (threadIdx.x >= off) ? tmp[threadIdx.x - off] : 0;
      __syncthreads();
      tmp[threadIdx.x] += t;
      __syncthreads();
    }
    if (i < P) part[i] = tmp[threadIdx.x] - v + carry;
    __syncthreads();
    if (threadIdx.x == 0) carry += tmp[255];
    __syncthreads();
  }
  if (threadIdx.x == 0) *totalout = carry;
}

__global__ __launch_bounds__(256) void scan3(int* __restrict__ outp,
    const int* __restrict__ part, int n) {
  int gid = blockIdx.x * 256 + threadIdx.x;
  if (gid < n) outp[gid] += part[blockIdx.x];
}

__global__ __launch_bounds__(256) void copy_int(const int* __restrict__ src,
                                                int* __restrict__ dst, int n) {
  int i = blockIdx.x * 256 + threadIdx.x;
  if (i < n) dst[i] = src[i];
}

__global__ __launch_bounds__(256) void fill_csr(const int* __restrict__ es,
    const int* __restrict__ ed, int* __restrict__ cursor, int* __restrict__ col, int E) {
  int i = blockIdx.x * 256 + threadIdx.x;
  if (i < E) {
    int pos = atomicAdd(&cursor[ed[i]], 1);
    col[pos] = es[i];
  }
}

// wout(bf16) = W[o0] + W[o1] (+ W[o2]); bout(f32) similarly; offsets in elements
__global__ __launch_bounds__(256) void wsum_kernel(
    const void* __restrict__ W, int o0, int o1, int o2,
    const void* __restrict__ B, int p0, int p1, int p2,
    const int* __restrict__ flagp, __hip_bfloat16* __restrict__ wout,
    float* __restrict__ bout, int wsz) {
  const bool bf = (*flagp != 0);
  int i = blockIdx.x * 256 + threadIdx.x;
  float s = 0.0f, sb = 0.0f;
  if (bf) {
    const __hip_bfloat16* Wp = (const __hip_bfloat16*)W;
    const __hip_bfloat16* Bp = (const __hip_bfloat16*)B;
    if (i < wsz) {
      s = __bfloat162float(Wp[o0 + i]) + __bfloat162float(Wp[o1 + i]);
      if (o2 >= 0) s += __bfloat162float(Wp[o2 + i]);
    }
    if (i < 64) {
      sb = __bfloat162float(Bp[p0 + i]) + __bfloat162float(Bp[p1 + i]);
      if (p2 >= 0) sb += __bfloat162float(Bp[p2 + i]);
    }
  } else {
    const float* Wp = (const float*)W;
    const float* Bp = (const float*)B;
    if (i < wsz) {
      s = Wp[o0 + i] + Wp[o1 + i];
      if (o2 >= 0) s += Wp[o2 + i];
    }
    if (i < 64) {
      sb = Bp[p0 + i] + Bp[p1 + i];
      if (p2 >= 0) sb += Bp[p2 + i];
    }
  }
  if (i < wsz) wout[i] = __float2bfloat16(s);
  if (i < 64) bout[i] = sb;
}

extern "C" void kernel_launch(void* const* d_in, const int* in_sizes, int n_in,
                              void* d_out, int out_size, void* d_ws, size_t ws_size,
                              hipStream_t stream) {
  const int NC = 100000, NM = 50000, ND = 25000;
  const int nn[3] = {NC, NM, ND};
  const size_t toff[3] = {0, (size_t)NC * 64, (size_t)(NC + NM) * 64};
  const void* X[3] = {d_in[0], d_in[1], d_in[2]};
  const int* eptr[8]; int E[8];
  for (int r = 0; r < 8; ++r) { eptr[r] = (const int*)d_in[3 + r]; E[r] = in_sizes[3 + r] / 2; }
  const void* Wls[3] = {d_in[11], d_in[14], d_in[17]};
  const void* Wrs[3] = {d_in[12], d_in[15], d_in[18]};
  const void* Bbs[3] = {d_in[13], d_in[16], d_in[19]};

  // relation r: 0:c->m 1:m->d 2:c->d 3:m->c 4:d->m 5:d->c 6:c->c 7:m->m
  const int src_t[8] = {0, 1, 0, 1, 2, 2, 0, 1};
  const int dst_t[8] = {1, 2, 2, 0, 1, 0, 0, 1};
  // relations per dst type (3rd used only in layer 3 for T=0,1)
  const int relT[3][3] = {{3, 5, 6}, {0, 4, 7}, {1, 2, -1}};

  int coff[8]; int cntN = 0;
  for (int r = 0; r < 8; ++r) { coff[r] = cntN; cntN += nn[dst_t[r]]; }
  int Etot = 0; for (int r = 0; r < 8; ++r) Etot += E[r];

  // ---- workspace carve (~60 MB; round-5 proved ws_size >= ~73 MB) ----
  char* base = (char*)d_ws;
  int* flag = (int*)base; base += 16;
  __hip_bfloat16* wr[3];
  for (int t = 0; t < 3; ++t) { wr[t] = (__hip_bfloat16*)base; base += 64 * 128 * 2; }
  float* bs[3]; for (int t = 0; t < 3; ++t) { bs[t] = (float*)base; base += 64 * 4; }
  __hip_bfloat16* y = (__hip_bfloat16*)base; base += (size_t)175000 * 64 * 2;  // max rows/phase
  int* degcur = (int*)base; base += (size_t)cntN * 4;
  int* rowptr = (int*)base; base += (size_t)(cntN + 1) * 4;
  int* part = (int*)base; base += (size_t)(DIV_UP(cntN, 256) + 1) * 4;
  int* col = (int*)base; base += (size_t)Etot * 4;
  __hip_bfloat16* h2 = (__hip_bfloat16*)base; base += (size_t)175000 * 64 * 2;
  __hip_bfloat16* h1 = (__hip_bfloat16*)d_out;  // prefix of d_out; dead before layer-3 writes
  (void)n_in; (void)out_size; (void)ws_size;

  detect_dtype<<<1, 256, 0, stream>>>((const unsigned int*)d_in[0], flag);

  // ---- CSR build (edges fixed; shared by all layers) ----
  hipMemsetAsync(degcur, 0, (size_t)cntN * sizeof(int), stream);
  for (int r = 0; r < 8; ++r)
    count_int<<<DIV_UP(E[r], 256), 256, 0, stream>>>(eptr[r] + E[r], degcur + coff[r], E[r]);
  int nb = DIV_UP(cntN, 256);
  scan1<<<nb, 256, 0, stream>>>(degcur, rowptr, part, cntN);
  scan2<<<1, 256, 0, stream>>>(part, nb, rowptr + cntN);
  scan3<<<nb, 256, 0, stream>>>(rowptr, part, cntN);
  copy_int<<<nb, 256, 0, stream>>>(rowptr, degcur, cntN);  // degcur -> cursor
  for (int r = 0; r < 8; ++r)
    fill_csr<<<DIV_UP(E[r], 256), 256, 0, stream>>>(eptr[r], eptr[r] + E[r],
                                                    degcur + coff[r], col, E[r]);

  for (int layer = 0; layer < 3; ++layer) {
    const void* Wl = Wls[layer];
    const void* Wr = Wrs[layer];
    const void* Bb = Bbs[layer];
    const int K = (layer == 0) ? 128 : 64;
    const int wsz = 64 * K;
    const __hip_bfloat16* hin = (layer == 1) ? h1 : h2;  // layer 0 uses X

    for (int T = 0; T < 3; ++T) {
      const int nrel = (layer == 2 && T < 2) ? 3 : 2;
      const int r0 = relT[T][0], r1 = relT[T][1];
      const int r2 = (nrel == 3) ? relT[T][2] : -1;
      wsum_kernel<<<DIV_UP(wsz, 256), 256, 0, stream>>>(
          Wr, r0 * wsz, r1 * wsz, (r2 >= 0) ? r2 * wsz : -1,
          Bb, r0 * 64, r1 * 64, (r2 >= 0) ? r2 * 64 : -1,
          flag, wr[T], bs[T], wsz);
      // y GEMMs for this dst type's relations
      size_t yoffs[3] = {0, 0, 0};
      size_t yoff = 0;
      for (int j = 0; j < nrel; ++j) {
        int r = relT[T][j], st = src_t[r];
        yoffs[j] = yoff;
        if (layer == 0)
          gemm_mfma<128><<<DIV_UP(nn[st], 64), 256, 0, stream>>>(
              X[st], 2, Wl, r * wsz, 2, flag, y + yoff, nn[st]);
        else
          gemm_mfma<64><<<DIV_UP(nn[st], 64), 256, 0, stream>>>(
              hin + toff[st], 1, Wl, r * wsz, 2, flag, y + yoff, nn[st]);
        yoff += (size_t)nn[st] * 64;
      }
      // fused lin_r + gather + epilogue
      const int* rp0 = rowptr + coff[r0];
      const int* rp1 = rowptr + coff[r1];
      const int* rp2 = (r2 >= 0) ? rowptr + coff[r2] : rp0;
      const __hip_bfloat16* y0 = y + yoffs[0];
      const __hip_bfloat16* y1 = y + yoffs[1];
      const __hip_bfloat16* y2 = (r2 >= 0) ? y + yoffs[2] : y0;
      int grid = DIV_UP(nn[T], 16);
      if (layer == 0) {
        fused_agg<128, 0, 2><<<grid, 256, 0, stream>>>(
            X[T], 2, flag, wr[T], bs[T], col, rp0, y0, rp1, y1, rp2, y2,
            0.5f, h1, toff[T], nn[T]);
      } else if (layer == 1) {
        fused_agg<64, 0, 2><<<grid, 256, 0, stream>>>(
            h1 + toff[T], 1, flag, wr[T], bs[T], col, rp0, y0, rp1, y1, rp2, y2,
            0.5f, h2, toff[T], nn[T]);
      } else if (T < 2) {
        fused_agg<64, 1, 3><<<grid, 256, 0, stream>>>(
            h2 + toff[T], 1, flag, wr[T], bs[T], col, rp0, y0, rp1, y1, rp2, y2,
            1.0f / 3.0f, d_out, toff[T], nn[T]);
      } else {
        fused_agg<64, 1, 2><<<grid, 256, 0, stream>>>(
            h2 + toff[T], 1, flag, wr[T], bs[T], col, rp0, y0, rp1, y1, rp2, y2,
            0.5f, d_out, toff[T], nn[T]);
      }
    }
  }
}

// Round 4
// 1101.790 us; speedup vs baseline: 1.2724x; 1.0146x over previous
//
#include <hip/hip_runtime.h>
#include <hip/hip_bf16.h>

#define DIV_UP(a,b) (((a)+(b)-1)/(b))

typedef __bf16 bf16x8 __attribute__((ext_vector_type(8)));
typedef float  f32x4  __attribute__((ext_vector_type(4)));

// ---- runtime dtype detector: bf16 data -> low 16b half of each word has a sane
// bf16 exponent; f32 data -> low half is mantissa garbage. flag=1 means bf16.
__global__ __launch_bounds__(256) void detect_dtype(const unsigned int* __restrict__ x,
                                                    int* __restrict__ flag) {
  __shared__ int cnt_s;
  if (threadIdx.x == 0) cnt_s = 0;
  __syncthreads();
  unsigned w = x[threadIdx.x];
  unsigned lo_exp = (w >> 7) & 0xFF;
  if (lo_exp >= 100 && lo_exp <= 140) atomicAdd(&cnt_s, 1);
  __syncthreads();
  if (threadIdx.x == 0) flag[0] = (cnt_s >= 128) ? 1 : 0;
}

// y[n,64] = x[n,K] @ w[64,K]^T via v_mfma_f32_16x16x32_bf16 (round-5 proven).
// xmode/wmode: 0 = f32 pointer, 1 = bf16 pointer, 2 = dual (use *flagp).
template<int K>
__global__ __launch_bounds__(256) void gemm_mfma(
    const void* __restrict__ x, int xmode,
    const void* __restrict__ w, int woff, int wmode,
    const int* __restrict__ flagp, __hip_bfloat16* __restrict__ out, int n) {
  constexpr int KP = K + 8;
  __shared__ __bf16 xs[64 * KP];
  const bool xb = (xmode == 2) ? (*flagp != 0) : (xmode == 1);
  const bool wb = (wmode == 2) ? (*flagp != 0) : (wmode == 1);
  const int t = threadIdx.x;
  const int wv = t >> 6;
  const int L = t & 63;
  const int m = L & 15, q = L >> 4;
  const int row0 = blockIdx.x * 64;
  const int col = wv * 16 + m;

  bf16x8 bfr[K / 32];
  if (wb) {
    const __bf16* wh = (const __bf16*)w + woff;
#pragma unroll
    for (int ks = 0; ks < K / 32; ++ks)
      bfr[ks] = *(const bf16x8*)&wh[col * K + ks * 32 + q * 8];
  } else {
    const float* wf = (const float*)w + woff;
#pragma unroll
    for (int ks = 0; ks < K / 32; ++ks) {
      bf16x8 b;
#pragma unroll
      for (int j = 0; j < 8; ++j) b[j] = (__bf16)wf[col * K + ks * 32 + q * 8 + j];
      bfr[ks] = b;
    }
  }

  constexpr int CH = K / 8;
  if (xb) {
    const __bf16* xh = (const __bf16*)x;
    for (int idx = t; idx < 64 * CH; idx += 256) {
      int r = idx / CH, c = idx % CH;
      int gr = row0 + r; gr = (gr < n) ? gr : (n - 1);
      *(bf16x8*)&xs[r * KP + c * 8] = *(const bf16x8*)&xh[(size_t)gr * K + c * 8];
    }
  } else {
    const float* xf = (const float*)x;
    for (int idx = t; idx < 64 * CH; idx += 256) {
      int r = idx / CH, c = idx % CH;
      int gr = row0 + r; gr = (gr < n) ? gr : (n - 1);
      const float* src = &xf[(size_t)gr * K + c * 8];
      bf16x8 v;
#pragma unroll
      for (int j = 0; j < 8; ++j) v[j] = (__bf16)src[j];
      *(bf16x8*)&xs[r * KP + c * 8] = v;
    }
  }
  __syncthreads();

  f32x4 acc[4] = {};
#pragma unroll
  for (int ks = 0; ks < K / 32; ++ks) {
#pragma unroll
    for (int rt = 0; rt < 4; ++rt) {
      bf16x8 a = *(const bf16x8*)&xs[(rt * 16 + m) * KP + ks * 32 + q * 8];
      acc[rt] = __builtin_amdgcn_mfma_f32_16x16x32_bf16(a, bfr[ks], acc[rt], 0, 0, 0);
    }
  }

#pragma unroll
  for (int rt = 0; rt < 4; ++rt) {
#pragma unroll
    for (int i = 0; i < 4; ++i) {
      int gr = row0 + rt * 16 + q * 4 + i;
      if (gr < n) out[(size_t)gr * 64 + col] = __float2bfloat16(acc[rt][i]);
    }
  }
}

// ======== fused per-(layer, dst-type): lin_r MFMA + row-per-wave multi-relation
// CSR gather + epilogue (relu->h / l2norm->out). Block = 256 (4 waves) per 16 dst
// rows; wave wv owns rows wv*4..wv*4+3 (round-0/3 proven structure).
// Round-4: 2-col/lane dword gather. Lane owns column pair (2j,2j+1); lanes 0-31
// walk even edge positions, 32-63 odd. Per edge: one 4B load (2 packed bf16),
// bit-op converts (w<<16 / w&0xffff0000). Clamp-to-last keeps overhang loads as
// cache hits (round-1 lesson: garbage-index loads add random traffic). Halves
// merged with one shfl_xor(32). Packed 4B/8B coalesced stores from half 0. ========
template<int K, int MODE, int NREL>  // MODE 0: relu->bf16; MODE 1: l2norm->flag dtype
__global__ __launch_bounds__(256) void fused_agg(
    const void* __restrict__ xdst, int xmode,
    const int* __restrict__ flagp,
    const __hip_bfloat16* __restrict__ wrsum,  // [64][K] bf16 (merged lin_r)
    const float* __restrict__ bias,            // [64] (merged)
    const int* __restrict__ col,               // shared CSR col array
    const int* __restrict__ rp0, const __hip_bfloat16* __restrict__ y0,
    const int* __restrict__ rp1, const __hip_bfloat16* __restrict__ y1,
    const int* __restrict__ rp2, const __hip_bfloat16* __restrict__ y2,
    float invR,
    void* __restrict__ outp, size_t obase, int n) {
  __shared__ float dbuf[16][68];
  __shared__ int rpl_s[NREL][17];   // rowptr[row0..row0+16] per relation
  const bool xb = (xmode == 2) ? (*flagp != 0) : (xmode == 1);
  const int t = threadIdx.x;
  const int wv = t >> 6, L = t & 63;
  const int m = L & 15, q = L >> 4;
  const int row0 = blockIdx.x * 16;
  const int colc = wv * 16 + m;

  // --- cooperative rowptr load (overlaps MFMA latency; existing sync covers it) ---
  if (t < NREL * 17) {
    int j = t / 17, k = t - j * 17;
    const int* rp = (j == 0) ? rp0 : (j == 1) ? rp1 : rp2;
    int gi = row0 + k; gi = (gi < n) ? gi : n;   // rows >= n -> zero-length spans
    rpl_s[j][k] = rp[gi];
  }

  // --- lin_r MFMA: B fragments = this wave's 16 cols of Wr_sum ---
  const __bf16* wh = (const __bf16*)wrsum;
  bf16x8 bfr[K / 32];
#pragma unroll
  for (int ks = 0; ks < K / 32; ++ks)
    bfr[ks] = *(const bf16x8*)&wh[colc * K + ks * 32 + q * 8];

  // A fragments: row (row0+m) of x_dst
  int ar = row0 + m; ar = (ar < n) ? ar : (n - 1);
  f32x4 acc = {};
  if (xb) {
    const __bf16* xp = (const __bf16*)xdst;
#pragma unroll
    for (int ks = 0; ks < K / 32; ++ks) {
      bf16x8 a = *(const bf16x8*)&xp[(size_t)ar * K + ks * 32 + q * 8];
      acc = __builtin_amdgcn_mfma_f32_16x16x32_bf16(a, bfr[ks], acc, 0, 0, 0);
    }
  } else {
    const float* xp = (const float*)xdst;
#pragma unroll
    for (int ks = 0; ks < K / 32; ++ks) {
      bf16x8 a;
#pragma unroll
      for (int j = 0; j < 8; ++j) a[j] = (__bf16)xp[(size_t)ar * K + ks * 32 + q * 8 + j];
      acc = __builtin_amdgcn_mfma_f32_16x16x32_bf16(a, bfr[ks], acc, 0, 0, 0);
    }
  }
  float bc = bias[colc];
#pragma unroll
  for (int i = 0; i < 4; ++i) dbuf[q * 4 + i][colc] = acc[i] + bc;  // D row = q*4+i
  __syncthreads();

  const __hip_bfloat16* ys[3] = {y0, y1, y2};
  const int jj = L & 31;        // column-pair index: cols 2jj, 2jj+1
  const int half = L >> 5;      // 0: even edge positions; 1: odd
  const char* ybL[NREL];
#pragma unroll
  for (int j = 0; j < NREL; ++j)
    ybL[j] = (const char*)ys[j] + (size_t)jj * 4;

#pragma unroll 1
  for (int rr = 0; rr < 4; ++rr) {
    const int lr = wv * 4 + rr;       // wave-uniform local row
    const int gr = row0 + lr;
    if (gr >= n) continue;

    // per-relation stream state (compile-time unrolled -> registers)
    int ptr[NREL], rem[NREL];
    float gg0[NREL], gg1[NREL], idg[NREL];
    int nb = 0;
#pragma unroll
    for (int j = 0; j < NREL; ++j) {
      int b0 = rpl_s[j][lr], e0 = rpl_s[j][lr + 1];
      int d = e0 - b0;
      ptr[j] = b0; rem[j] = d; gg0[j] = 0.0f; gg1[j] = 0.0f;
      idg[j] = (d > 0) ? (1.0f / (float)d) : 0.0f;
      int nbj = (d + 3) >> 2;
      nb = (nbj > nb) ? nbj : nb;
    }

#pragma unroll 1
    for (int b = 0; b < nb; ++b) {
      unsigned wd[NREL][2];
#pragma unroll
      for (int j = 0; j < NREL; ++j) {
        if (rem[j] > 0) {                      // wave-uniform guard
          int last = rem[j] - 1;
          int o0 = (half < last) ? half : last;          // clamp: cache-hit repeat
          int o1 = (2 + half < last) ? (2 + half) : last;
          int c0 = col[ptr[j] + o0];
          int c1 = col[ptr[j] + o1];
          wd[j][0] = *(const unsigned*)(ybL[j] + (size_t)c0 * 128);
          wd[j][1] = *(const unsigned*)(ybL[j] + (size_t)c1 * 128);
        }
      }
#pragma unroll
      for (int j = 0; j < NREL; ++j) {
        if (rem[j] > 0) {
          unsigned w0 = (half < rem[j]) ? wd[j][0] : 0u;
          unsigned w1 = (2 + half < rem[j]) ? wd[j][1] : 0u;
          gg0[j] += __uint_as_float(w0 << 16) + __uint_as_float(w1 << 16);
          gg1[j] += __uint_as_float(w0 & 0xffff0000u) + __uint_as_float(w1 & 0xffff0000u);
          ptr[j] += 4; rem[j] -= 4;
        }
      }
    }

    float t0 = 0.0f, t1 = 0.0f;
#pragma unroll
    for (int j = 0; j < NREL; ++j) { t0 += gg0[j] * idg[j]; t1 += gg1[j] * idg[j]; }
    t0 += __shfl_xor(t0, 32, 64);   // merge even/odd halves
    t1 += __shfl_xor(t1, 32, 64);
    float s0 = (dbuf[lr][2 * jj] + t0) * invR;
    float s1 = (dbuf[lr][2 * jj + 1] + t1) * invR;

    if (MODE == 0) {
      if (half == 0) {
        __hip_bfloat16 b0 = __float2bfloat16(fmaxf(s0, 0.0f));
        __hip_bfloat16 b1 = __float2bfloat16(fmaxf(s1, 0.0f));
        unsigned pw = ((unsigned)*(const unsigned short*)&b1 << 16) |
                      (unsigned)*(const unsigned short*)&b0;
        *(unsigned*)((__hip_bfloat16*)outp + obase + (size_t)gr * 64 + 2 * jj) = pw;
      }
    } else {
      float ss = s0 * s0 + s1 * s1;
#pragma unroll
      for (int o = 16; o > 0; o >>= 1) ss += __shfl_xor(ss, o, 64);  // within-half: full 64-col sum
      float sc = 1.0f / fmaxf(sqrtf(ss), 1e-12f);
      float r0 = s0 * sc, r1 = s1 * sc;
      if (half == 0) {
        size_t idx = obase + (size_t)gr * 64 + 2 * jj;
        if (*flagp) {
          __hip_bfloat16 b0 = __float2bfloat16(r0);
          __hip_bfloat16 b1 = __float2bfloat16(r1);
          unsigned pw = ((unsigned)*(const unsigned short*)&b1 << 16) |
                        (unsigned)*(const unsigned short*)&b0;
          *(unsigned*)((__hip_bfloat16*)outp + idx) = pw;
        } else {
          float2 v; v.x = r0; v.y = r1;
          *(float2*)((float*)outp + idx) = v;
        }
      }
    }
  }
}

// ======== CSR build (round-4 proven) ========
__global__ __launch_bounds__(256) void count_int(const int* __restrict__ ed,
                                                 int* __restrict__ deg, int E) {
  int i = blockIdx.x * 256 + threadIdx.x;
  if (i < E) atomicAdd(&deg[ed[i]], 1);
}

__global__ __launch_bounds__(256) void scan1(const int* __restrict__ deg,
    int* __restrict__ outp, int* __restrict__ part, int n) {
  __shared__ int tmp[256];
  int gid = blockIdx.x * 256 + threadIdx.x;
  int v = (gid < n) ? deg[gid] : 0;
  tmp[threadIdx.x] = v;
  __syncthreads();
  for (int off = 1; off < 256; off <<= 1) {
    int t = (threadIdx.x >= off) ? tmp[threadIdx.x - off] : 0;
    __syncthreads();
    tmp[threadIdx.x] += t;
    __syncthreads();
  }
  if (gid < n) outp[gid] = tmp[threadIdx.x] - v;  // exclusive
  if (threadIdx.x == 255) part[blockIdx.x] = tmp[255];
}

__global__ __launch_bounds__(256) void scan2(int* __restrict__ part, int P,
                                             int* __restrict__ totalout) {
  __shared__ int tmp[256];
  __shared__ int carry;
  if (threadIdx.x == 0) carry = 0;
  __syncthreads();
  for (int base0 = 0; base0 < P; base0 += 256) {
    int i = base0 + threadIdx.x;
    int v = (i < P) ? part[i] : 0;
    tmp[threadIdx.x] = v;
    __syncthreads();
    for (int off = 1; off < 256; off <<= 1) {
      int t = (threadIdx.x >= off) ? tmp[threadIdx.x - off] : 0;
      __syncthreads();
      tmp[threadIdx.x] += t;
      __syncthreads();
    }
    if (i < P) part[i] = tmp[threadIdx.x] - v + carry;
    __syncthreads();
    if (threadIdx.x == 0) carry += tmp[255];
    __syncthreads();
  }
  if (threadIdx.x == 0) *totalout = carry;
}

__global__ __launch_bounds__(256) void scan3(int* __restrict__ outp,
    const int* __restrict__ part, int n) {
  int gid = blockIdx.x * 256 + threadIdx.x;
  if (gid < n) outp[gid] += part[blockIdx.x];
}

__global__ __launch_bounds__(256) void copy_int(const int* __restrict__ src,
                                                int* __restrict__ dst, int n) {
  int i = blockIdx.x * 256 + threadIdx.x;
  if (i < n) dst[i] = src[i];
}

__global__ __launch_bounds__(256) void fill_csr(const int* __restrict__ es,
    const int* __restrict__ ed, int* __restrict__ cursor, int* __restrict__ col, int E) {
  int i = blockIdx.x * 256 + threadIdx.x;
  if (i < E) {
    int pos = atomicAdd(&cursor[ed[i]], 1);
    col[pos] = es[i];
  }
}

// wout(bf16) = W[o0] + W[o1] (+ W[o2]); bout(f32) similarly; offsets in elements
__global__ __launch_bounds__(256) void wsum_kernel(
    const void* __restrict__ W, int o0, int o1, int o2,
    const void* __restrict__ B, int p0, int p1, int p2,
    const int* __restrict__ flagp, __hip_bfloat16* __restrict__ wout,
    float* __restrict__ bout, int wsz) {
  const bool bf = (*flagp != 0);
  int i = blockIdx.x * 256 + threadIdx.x;
  float s = 0.0f, sb = 0.0f;
  if (bf) {
    const __hip_bfloat16* Wp = (const __hip_bfloat16*)W;
    const __hip_bfloat16* Bp = (const __hip_bfloat16*)B;
    if (i < wsz) {
      s = __bfloat162float(Wp[o0 + i]) + __bfloat162float(Wp[o1 + i]);
      if (o2 >= 0) s += __bfloat162float(Wp[o2 + i]);
    }
    if (i < 64) {
      sb = __bfloat162float(Bp[p0 + i]) + __bfloat162float(Bp[p1 + i]);
      if (p2 >= 0) sb += __bfloat162float(Bp[p2 + i]);
    }
  } else {
    const float* Wp = (const float*)W;
    const float* Bp = (const float*)B;
    if (i < wsz) {
      s = Wp[o0 + i] + Wp[o1 + i];
      if (o2 >= 0) s += Wp[o2 + i];
    }
    if (i < 64) {
      sb = Bp[p0 + i] + Bp[p1 + i];
      if (p2 >= 0) sb += Bp[p2 + i];
    }
  }
  if (i < wsz) wout[i] = __float2bfloat16(s);
  if (i < 64) bout[i] = sb;
}

extern "C" void kernel_launch(void* const* d_in, const int* in_sizes, int n_in,
                              void* d_out, int out_size, void* d_ws, size_t ws_size,
                              hipStream_t stream) {
  const int NC = 100000, NM = 50000, ND = 25000;
  const int nn[3] = {NC, NM, ND};
  const size_t toff[3] = {0, (size_t)NC * 64, (size_t)(NC + NM) * 64};
  const void* X[3] = {d_in[0], d_in[1], d_in[2]};
  const int* eptr[8]; int E[8];
  for (int r = 0; r < 8; ++r) { eptr[r] = (const int*)d_in[3 + r]; E[r] = in_sizes[3 + r] / 2; }
  const void* Wls[3] = {d_in[11], d_in[14], d_in[17]};
  const void* Wrs[3] = {d_in[12], d_in[15], d_in[18]};
  const void* Bbs[3] = {d_in[13], d_in[16], d_in[19]};

  // relation r: 0:c->m 1:m->d 2:c->d 3:m->c 4:d->m 5:d->c 6:c->c 7:m->m
  const int src_t[8] = {0, 1, 0, 1, 2, 2, 0, 1};
  const int dst_t[8] = {1, 2, 2, 0, 1, 0, 0, 1};
  // relations per dst type (3rd used only in layer 3 for T=0,1)
  const int relT[3][3] = {{3, 5, 6}, {0, 4, 7}, {1, 2, -1}};

  int coff[8]; int cntN = 0;
  for (int r = 0; r < 8; ++r) { coff[r] = cntN; cntN += nn[dst_t[r]]; }
  int Etot = 0; for (int r = 0; r < 8; ++r) Etot += E[r];

  // ---- workspace carve (~60 MB; round-5 proved ws_size >= ~73 MB) ----
  char* base = (char*)d_ws;
  int* flag = (int*)base; base += 16;
  __hip_bfloat16* wr[3];
  for (int t = 0; t < 3; ++t) { wr[t] = (__hip_bfloat16*)base; base += 64 * 128 * 2; }
  float* bs[3]; for (int t = 0; t < 3; ++t) { bs[t] = (float*)base; base += 64 * 4; }
  __hip_bfloat16* y = (__hip_bfloat16*)base; base += (size_t)175000 * 64 * 2;  // max rows/phase
  int* degcur = (int*)base; base += (size_t)cntN * 4;
  int* rowptr = (int*)base; base += (size_t)(cntN + 1) * 4;
  int* part = (int*)base; base += (size_t)(DIV_UP(cntN, 256) + 1) * 4;
  int* col = (int*)base; base += (size_t)Etot * 4;
  __hip_bfloat16* h2 = (__hip_bfloat16*)base; base += (size_t)175000 * 64 * 2;
  __hip_bfloat16* h1 = (__hip_bfloat16*)d_out;  // prefix of d_out; dead before layer-3 writes
  (void)n_in; (void)out_size; (void)ws_size;

  detect_dtype<<<1, 256, 0, stream>>>((const unsigned int*)d_in[0], flag);

  // ---- CSR build (edges fixed; shared by all layers) ----
  hipMemsetAsync(degcur, 0, (size_t)cntN * sizeof(int), stream);
  for (int r = 0; r < 8; ++r)
    count_int<<<DIV_UP(E[r], 256), 256, 0, stream>>>(eptr[r] + E[r], degcur + coff[r], E[r]);
  int nb = DIV_UP(cntN, 256);
  scan1<<<nb, 256, 0, stream>>>(degcur, rowptr, part, cntN);
  scan2<<<1, 256, 0, stream>>>(part, nb, rowptr + cntN);
  scan3<<<nb, 256, 0, stream>>>(rowptr, part, cntN);
  copy_int<<<nb, 256, 0, stream>>>(rowptr, degcur, cntN);  // degcur -> cursor
  for (int r = 0; r < 8; ++r)
    fill_csr<<<DIV_UP(E[r], 256), 256, 0, stream>>>(eptr[r], eptr[r] + E[r],
                                                    degcur + coff[r], col, E[r]);

  for (int layer = 0; layer < 3; ++layer) {
    const void* Wl = Wls[layer];
    const void* Wr = Wrs[layer];
    const void* Bb = Bbs[layer];
    const int K = (layer == 0) ? 128 : 64;
    const int wsz = 64 * K;
    const __hip_bfloat16* hin = (layer == 1) ? h1 : h2;  // layer 0 uses X

    for (int T = 0; T < 3; ++T) {
      const int nrel = (layer == 2 && T < 2) ? 3 : 2;
      const int r0 = relT[T][0], r1 = relT[T][1];
      const int r2 = (nrel == 3) ? relT[T][2] : -1;
      wsum_kernel<<<DIV_UP(wsz, 256), 256, 0, stream>>>(
          Wr, r0 * wsz, r1 * wsz, (r2 >= 0) ? r2 * wsz : -1,
          Bb, r0 * 64, r1 * 64, (r2 >= 0) ? r2 * 64 : -1,
          flag, wr[T], bs[T], wsz);
      // y GEMMs for this dst type's relations
      size_t yoffs[3] = {0, 0, 0};
      size_t yoff = 0;
      for (int j = 0; j < nrel; ++j) {
        int r = relT[T][j], st = src_t[r];
        yoffs[j] = yoff;
        if (layer == 0)
          gemm_mfma<128><<<DIV_UP(nn[st], 64), 256, 0, stream>>>(
              X[st], 2, Wl, r * wsz, 2, flag, y + yoff, nn[st]);
        else
          gemm_mfma<64><<<DIV_UP(nn[st], 64), 256, 0, stream>>>(
              hin + toff[st], 1, Wl, r * wsz, 2, flag, y + yoff, nn[st]);
        yoff += (size_t)nn[st] * 64;
      }
      // fused lin_r + gather + epilogue
      const int* rp0 = rowptr + coff[r0];
      const int* rp1 = rowptr + coff[r1];
      const int* rp2 = (r2 >= 0) ? rowptr + coff[r2] : rp0;
      const __hip_bfloat16* y0 = y + yoffs[0];
      const __hip_bfloat16* y1 = y + yoffs[1];
      const __hip_bfloat16* y2 = (r2 >= 0) ? y + yoffs[2] : y0;
      int grid = DIV_UP(nn[T], 16);
      if (layer == 0) {
        fused_agg<128, 0, 2><<<grid, 256, 0, stream>>>(
            X[T], 2, flag, wr[T], bs[T], col, rp0, y0, rp1, y1, rp2, y2,
            0.5f, h1, toff[T], nn[T]);
      } else if (layer == 1) {
        fused_agg<64, 0, 2><<<grid, 256, 0, stream>>>(
            h1 + toff[T], 1, flag, wr[T], bs[T], col, rp0, y0, rp1, y1, rp2, y2,
            0.5f, h2, toff[T], nn[T]);
      } else if (T < 2) {
        fused_agg<64, 1, 3><<<grid, 256, 0, stream>>>(
            h2 + toff[T], 1, flag, wr[T], bs[T], col, rp0, y0, rp1, y1, rp2, y2,
            1.0f / 3.0f, d_out, toff[T], nn[T]);
      } else {
        fused_agg<64, 1, 2><<<grid, 256, 0, stream>>>(
            h2 + toff[T], 1, flag, wr[T], bs[T], col, rp0, y0, rp1, y1, rp2, y2,
            0.5f, d_out, toff[T], nn[T]);
      }
    }
  }
}

// Round 5
// 1096.822 us; speedup vs baseline: 1.2782x; 1.0045x over previous
//
#include <hip/hip_runtime.h>
#include <hip/hip_bf16.h>

#define DIV_UP(a,b) (((a)+(b)-1)/(b))

typedef __bf16 bf16x8 __attribute__((ext_vector_type(8)));
typedef float  f32x4  __attribute__((ext_vector_type(4)));

// ---- runtime dtype detector: bf16 data -> low 16b half of each word has a sane
// bf16 exponent; f32 data -> low half is mantissa garbage. flag=1 means bf16.
__global__ __launch_bounds__(256) void detect_dtype(const unsigned int* __restrict__ x,
                                                    int* __restrict__ flag) {
  __shared__ int cnt_s;
  if (threadIdx.x == 0) cnt_s = 0;
  __syncthreads();
  unsigned w = x[threadIdx.x];
  unsigned lo_exp = (w >> 7) & 0xFF;
  if (lo_exp >= 100 && lo_exp <= 140) atomicAdd(&cnt_s, 1);
  __syncthreads();
  if (threadIdx.x == 0) flag[0] = (cnt_s >= 128) ? 1 : 0;
}

// y[n,64] = x[n,K] @ w[64,K]^T via v_mfma_f32_16x16x32_bf16 (round-5 proven).
// xmode/wmode: 0 = f32 pointer, 1 = bf16 pointer, 2 = dual (use *flagp).
template<int K>
__global__ __launch_bounds__(256) void gemm_mfma(
    const void* __restrict__ x, int xmode,
    const void* __restrict__ w, int woff, int wmode,
    const int* __restrict__ flagp, __hip_bfloat16* __restrict__ out, int n) {
  constexpr int KP = K + 8;
  __shared__ __bf16 xs[64 * KP];
  const bool xb = (xmode == 2) ? (*flagp != 0) : (xmode == 1);
  const bool wb = (wmode == 2) ? (*flagp != 0) : (wmode == 1);
  const int t = threadIdx.x;
  const int wv = t >> 6;
  const int L = t & 63;
  const int m = L & 15, q = L >> 4;
  const int row0 = blockIdx.x * 64;
  const int col = wv * 16 + m;

  bf16x8 bfr[K / 32];
  if (wb) {
    const __bf16* wh = (const __bf16*)w + woff;
#pragma unroll
    for (int ks = 0; ks < K / 32; ++ks)
      bfr[ks] = *(const bf16x8*)&wh[col * K + ks * 32 + q * 8];
  } else {
    const float* wf = (const float*)w + woff;
#pragma unroll
    for (int ks = 0; ks < K / 32; ++ks) {
      bf16x8 b;
#pragma unroll
      for (int j = 0; j < 8; ++j) b[j] = (__bf16)wf[col * K + ks * 32 + q * 8 + j];
      bfr[ks] = b;
    }
  }

  constexpr int CH = K / 8;
  if (xb) {
    const __bf16* xh = (const __bf16*)x;
    for (int idx = t; idx < 64 * CH; idx += 256) {
      int r = idx / CH, c = idx % CH;
      int gr = row0 + r; gr = (gr < n) ? gr : (n - 1);
      *(bf16x8*)&xs[r * KP + c * 8] = *(const bf16x8*)&xh[(size_t)gr * K + c * 8];
    }
  } else {
    const float* xf = (const float*)x;
    for (int idx = t; idx < 64 * CH; idx += 256) {
      int r = idx / CH, c = idx % CH;
      int gr = row0 + r; gr = (gr < n) ? gr : (n - 1);
      const float* src = &xf[(size_t)gr * K + c * 8];
      bf16x8 v;
#pragma unroll
      for (int j = 0; j < 8; ++j) v[j] = (__bf16)src[j];
      *(bf16x8*)&xs[r * KP + c * 8] = v;
    }
  }
  __syncthreads();

  f32x4 acc[4] = {};
#pragma unroll
  for (int ks = 0; ks < K / 32; ++ks) {
#pragma unroll
    for (int rt = 0; rt < 4; ++rt) {
      bf16x8 a = *(const bf16x8*)&xs[(rt * 16 + m) * KP + ks * 32 + q * 8];
      acc[rt] = __builtin_amdgcn_mfma_f32_16x16x32_bf16(a, bfr[ks], acc[rt], 0, 0, 0);
    }
  }

#pragma unroll
  for (int rt = 0; rt < 4; ++rt) {
#pragma unroll
    for (int i = 0; i < 4; ++i) {
      int gr = row0 + rt * 16 + q * 4 + i;
      if (gr < n) out[(size_t)gr * 64 + col] = __float2bfloat16(acc[rt][i]);
    }
  }
}

// ======== fused per-(layer, dst-type): lin_r MFMA + row-per-wave multi-relation
// CSR gather + epilogue (relu->h / l2norm->out). Block = 256 (4 waves) per 16 dst
// rows; wave wv owns rows wv*4..wv*4+3.
// Round-5: 2-row x NREL stream interleave (2 passes of 2 rows). All streams' col
// loads issue together, then all y loads (up to 12 lines in flight vs ~4-6),
// then masked accumulate -- halves the serial latency windows per wave while
// keeping persistent VGPR <= ~64 (occupancy step). saddr addressing: 32-bit byte
// offset (c<<7 | jj<<2) on uniform y base kills 64-bit per-lane address adds.
// Gather semantics (clamp-to-last = cache-hit repeat, masks) identical to the
// round-4 kernel that passed. ========
template<int K, int MODE, int NREL>  // MODE 0: relu->bf16; MODE 1: l2norm->flag dtype
__global__ __launch_bounds__(256) void fused_agg(
    const void* __restrict__ xdst, int xmode,
    const int* __restrict__ flagp,
    const __hip_bfloat16* __restrict__ wrsum,  // [64][K] bf16 (merged lin_r)
    const float* __restrict__ bias,            // [64] (merged)
    const int* __restrict__ col,               // shared CSR col array
    const int* __restrict__ rp0, const __hip_bfloat16* __restrict__ y0,
    const int* __restrict__ rp1, const __hip_bfloat16* __restrict__ y1,
    const int* __restrict__ rp2, const __hip_bfloat16* __restrict__ y2,
    float invR,
    void* __restrict__ outp, size_t obase, int n) {
  __shared__ float dbuf[16][68];
  __shared__ int rpl_s[NREL][17];   // rowptr[row0..row0+16] per relation
  const bool xb = (xmode == 2) ? (*flagp != 0) : (xmode == 1);
  const int t = threadIdx.x;
  const int wv = t >> 6, L = t & 63;
  const int m = L & 15, q = L >> 4;
  const int row0 = blockIdx.x * 16;
  const int colc = wv * 16 + m;

  // --- cooperative rowptr load (overlaps MFMA latency; existing sync covers it) ---
  if (t < NREL * 17) {
    int j = t / 17, k = t - j * 17;
    const int* rp = (j == 0) ? rp0 : (j == 1) ? rp1 : rp2;
    int gi = row0 + k; gi = (gi < n) ? gi : n;   // rows >= n -> zero-length spans
    rpl_s[j][k] = rp[gi];
  }

  // --- lin_r MFMA: B fragments = this wave's 16 cols of Wr_sum ---
  const __bf16* wh = (const __bf16*)wrsum;
  bf16x8 bfr[K / 32];
#pragma unroll
  for (int ks = 0; ks < K / 32; ++ks)
    bfr[ks] = *(const bf16x8*)&wh[colc * K + ks * 32 + q * 8];

  // A fragments: row (row0+m) of x_dst
  int ar = row0 + m; ar = (ar < n) ? ar : (n - 1);
  f32x4 acc = {};
  if (xb) {
    const __bf16* xp = (const __bf16*)xdst;
#pragma unroll
    for (int ks = 0; ks < K / 32; ++ks) {
      bf16x8 a = *(const bf16x8*)&xp[(size_t)ar * K + ks * 32 + q * 8];
      acc = __builtin_amdgcn_mfma_f32_16x16x32_bf16(a, bfr[ks], acc, 0, 0, 0);
    }
  } else {
    const float* xp = (const float*)xdst;
#pragma unroll
    for (int ks = 0; ks < K / 32; ++ks) {
      bf16x8 a;
#pragma unroll
      for (int j = 0; j < 8; ++j) a[j] = (__bf16)xp[(size_t)ar * K + ks * 32 + q * 8 + j];
      acc = __builtin_amdgcn_mfma_f32_16x16x32_bf16(a, bfr[ks], acc, 0, 0, 0);
    }
  }
  float bc = bias[colc];
#pragma unroll
  for (int i = 0; i < 4; ++i) dbuf[q * 4 + i][colc] = acc[i] + bc;  // D row = q*4+i
  __syncthreads();

  const char* ys[3] = {(const char*)y0, (const char*)y1, (const char*)y2};
  const int jj = L & 31;            // column-pair index: cols 2jj, 2jj+1
  const int half = L >> 5;          // 0: even edge positions; 1: odd
  const unsigned jb = (unsigned)jj << 2;   // byte offset of this lane's pair

#pragma unroll 1
  for (int pass = 0; pass < 2; ++pass) {
    // per-(row u, relation j) stream state; all indices compile-time (rule #20)
    int b0[2][NREL], dg[2][NREL];
    float g0[2][NREL], g1[2][NREL];
    int nbmax = 0;
#pragma unroll
    for (int u = 0; u < 2; ++u) {
      const int lr = wv * 4 + pass * 2 + u;
#pragma unroll
      for (int j = 0; j < NREL; ++j) {
        int s = rpl_s[j][lr], e = rpl_s[j][lr + 1];
        b0[u][j] = s; dg[u][j] = e - s;
        g0[u][j] = 0.0f; g1[u][j] = 0.0f;
        int nbj = (e - s + 3) >> 2;
        nbmax = (nbj > nbmax) ? nbj : nbmax;
      }
    }

#pragma unroll 1
    for (int b = 0; b < nbmax; ++b) {
      const int bb = b << 2;
      unsigned wd[2][NREL][2];
      // phase 1+2: col loads and y loads for every active stream (interleaved
      // issue; up to 2*NREL*2 y lines in flight)
#pragma unroll
      for (int u = 0; u < 2; ++u)
#pragma unroll
        for (int j = 0; j < NREL; ++j) {
          int rem = dg[u][j] - bb;
          if (rem > 0) {                       // wave-uniform guard
            int last = rem - 1;
            int o0 = (half < last) ? half : last;          // clamp: cache-hit repeat
            int o1 = (2 + half < last) ? (2 + half) : last;
            int p = b0[u][j] + bb;
            unsigned c0 = (unsigned)col[p + o0];
            unsigned c1 = (unsigned)col[p + o1];
            wd[u][j][0] = *(const unsigned*)(ys[j] + ((c0 << 7) + jb));
            wd[u][j][1] = *(const unsigned*)(ys[j] + ((c1 << 7) + jb));
          }
        }
      // phase 3: masked accumulate
#pragma unroll
      for (int u = 0; u < 2; ++u)
#pragma unroll
        for (int j = 0; j < NREL; ++j) {
          int rem = dg[u][j] - bb;
          if (rem > 0) {
            unsigned w0 = (half < rem) ? wd[u][j][0] : 0u;
            unsigned w1 = (2 + half < rem) ? wd[u][j][1] : 0u;
            g0[u][j] += __uint_as_float(w0 << 16) + __uint_as_float(w1 << 16);
            g1[u][j] += __uint_as_float(w0 & 0xffff0000u) + __uint_as_float(w1 & 0xffff0000u);
          }
        }
    }

    // epilogue for this pass's 2 rows
#pragma unroll
    for (int u = 0; u < 2; ++u) {
      const int lr = wv * 4 + pass * 2 + u;
      const int gr = row0 + lr;
      if (gr >= n) continue;                   // wave-uniform
      float t0 = 0.0f, t1 = 0.0f;
#pragma unroll
      for (int j = 0; j < NREL; ++j) {
        float idg = (dg[u][j] > 0) ? (1.0f / (float)dg[u][j]) : 0.0f;
        t0 += g0[u][j] * idg; t1 += g1[u][j] * idg;
      }
      t0 += __shfl_xor(t0, 32, 64);            // merge even/odd halves
      t1 += __shfl_xor(t1, 32, 64);
      float2 d2 = *(const float2*)&dbuf[lr][2 * jj];
      float s0 = (d2.x + t0) * invR;
      float s1 = (d2.y + t1) * invR;

      if (MODE == 0) {
        if (half == 0) {
          __hip_bfloat16 b0v = __float2bfloat16(fmaxf(s0, 0.0f));
          __hip_bfloat16 b1v = __float2bfloat16(fmaxf(s1, 0.0f));
          unsigned pw = ((unsigned)*(const unsigned short*)&b1v << 16) |
                        (unsigned)*(const unsigned short*)&b0v;
          *(unsigned*)((__hip_bfloat16*)outp + obase + (size_t)gr * 64 + 2 * jj) = pw;
        }
      } else {
        float ss = s0 * s0 + s1 * s1;
#pragma unroll
        for (int o = 16; o > 0; o >>= 1) ss += __shfl_xor(ss, o, 64);  // full 64-col sum per half
        float sc = 1.0f / fmaxf(sqrtf(ss), 1e-12f);
        float r0 = s0 * sc, r1 = s1 * sc;
        if (half == 0) {
          size_t idx = obase + (size_t)gr * 64 + 2 * jj;
          if (*flagp) {
            __hip_bfloat16 b0v = __float2bfloat16(r0);
            __hip_bfloat16 b1v = __float2bfloat16(r1);
            unsigned pw = ((unsigned)*(const unsigned short*)&b1v << 16) |
                          (unsigned)*(const unsigned short*)&b0v;
            *(unsigned*)((__hip_bfloat16*)outp + idx) = pw;
          } else {
            float2 v; v.x = r0; v.y = r1;
            *(float2*)((float*)outp + idx) = v;
          }
        }
      }
    }
  }
}

// ======== CSR build (round-4 proven) ========
__global__ __launch_bounds__(256) void count_int(const int* __restrict__ ed,
                                                 int* __restrict__ deg, int E) {
  int i = blockIdx.x * 256 + threadIdx.x;
  if (i < E) atomicAdd(&deg[ed[i]], 1);
}

__global__ __launch_bounds__(256) void scan1(const int* __restrict__ deg,
    int* __restrict__ outp, int* __restrict__ part, int n) {
  __shared__ int tmp[256];
  int gid = blockIdx.x * 256 + threadIdx.x;
  int v = (gid < n) ? deg[gid] : 0;
  tmp[threadIdx.x] = v;
  __syncthreads();
  for (int off = 1; off < 256; off <<= 1) {
    int t = (threadIdx.x >= off) ? tmp[threadIdx.x - off] : 0;
    __syncthreads();
    tmp[threadIdx.x] += t;
    __syncthreads();
  }
  if (gid < n) outp[gid] = tmp[threadIdx.x] - v;  // exclusive
  if (threadIdx.x == 255) part[blockIdx.x] = tmp[255];
}

__global__ __launch_bounds__(256) void scan2(int* __restrict__ part, int P,
                                             int* __restrict__ totalout) {
  __shared__ int tmp[256];
  __shared__ int carry;
  if (threadIdx.x == 0) carry = 0;
  __syncthreads();
  for (int base0 = 0; base0 < P; base0 += 256) {
    int i = base0 + threadIdx.x;
    int v = (i < P) ? part[i] : 0;
    tmp[threadIdx.x] = v;
    __syncthreads();
    for (int off = 1; off < 256; off <<= 1) {
      int t = (threadIdx.x >= off) ? tmp[threadIdx.x - off] : 0;
      __syncthreads();
      tmp[threadIdx.x] += t;
      __syncthreads();
    }
    if (i < P) part[i] = tmp[threadIdx.x] - v + carry;
    __syncthreads();
    if (threadIdx.x == 0) carry += tmp[255];
    __syncthreads();
  }
  if (threadIdx.x == 0) *totalout = carry;
}

__global__ __launch_bounds__(256) void scan3(int* __restrict__ outp,
    const int* __restrict__ part, int n) {
  int gid = blockIdx.x * 256 + threadIdx.x;
  if (gid < n) outp[gid] += part[blockIdx.x];
}

__global__ __launch_bounds__(256) void copy_int(const int* __restrict__ src,
                                                int* __restrict__ dst, int n) {
  int i = blockIdx.x * 256 + threadIdx.x;
  if (i < n) dst[i] = src[i];
}

__global__ __launch_bounds__(256) void fill_csr(const int* __restrict__ es,
    const int* __restrict__ ed, int* __restrict__ cursor, int* __restrict__ col, int E) {
  int i = blockIdx.x * 256 + threadIdx.x;
  if (i < E) {
    int pos = atomicAdd(&cursor[ed[i]], 1);
    col[pos] = es[i];
  }
}

// wout(bf16) = W[o0] + W[o1] (+ W[o2]); bout(f32) similarly; offsets in elements
__global__ __launch_bounds__(256) void wsum_kernel(
    const void* __restrict__ W, int o0, int o1, int o2,
    const void* __restrict__ B, int p0, int p1, int p2,
    const int* __restrict__ flagp, __hip_bfloat16* __restrict__ wout,
    float* __restrict__ bout, int wsz) {
  const bool bf = (*flagp != 0);
  int i = blockIdx.x * 256 + threadIdx.x;
  float s = 0.0f, sb = 0.0f;
  if (bf) {
    const __hip_bfloat16* Wp = (const __hip_bfloat16*)W;
    const __hip_bfloat16* Bp = (const __hip_bfloat16*)B;
    if (i < wsz) {
      s = __bfloat162float(Wp[o0 + i]) + __bfloat162float(Wp[o1 + i]);
      if (o2 >= 0) s += __bfloat162float(Wp[o2 + i]);
    }
    if (i < 64) {
      sb = __bfloat162float(Bp[p0 + i]) + __bfloat162float(Bp[p1 + i]);
      if (p2 >= 0) sb += __bfloat162float(Bp[p2 + i]);
    }
  } else {
    const float* Wp = (const float*)W;
    const float* Bp = (const float*)B;
    if (i < wsz) {
      s = Wp[o0 + i] + Wp[o1 + i];
      if (o2 >= 0) s += Wp[o2 + i];
    }
    if (i < 64) {
      sb = Bp[p0 + i] + Bp[p1 + i];
      if (p2 >= 0) sb += Bp[p2 + i];
    }
  }
  if (i < wsz) wout[i] = __float2bfloat16(s);
  if (i < 64) bout[i] = sb;
}

extern "C" void kernel_launch(void* const* d_in, const int* in_sizes, int n_in,
                              void* d_out, int out_size, void* d_ws, size_t ws_size,
                              hipStream_t stream) {
  const int NC = 100000, NM = 50000, ND = 25000;
  const int nn[3] = {NC, NM, ND};
  const size_t toff[3] = {0, (size_t)NC * 64, (size_t)(NC + NM) * 64};
  const void* X[3] = {d_in[0], d_in[1], d_in[2]};
  const int* eptr[8]; int E[8];
  for (int r = 0; r < 8; ++r) { eptr[r] = (const int*)d_in[3 + r]; E[r] = in_sizes[3 + r] / 2; }
  const void* Wls[3] = {d_in[11], d_in[14], d_in[17]};
  const void* Wrs[3] = {d_in[12], d_in[15], d_in[18]};
  const void* Bbs[3] = {d_in[13], d_in[16], d_in[19]};

  // relation r: 0:c->m 1:m->d 2:c->d 3:m->c 4:d->m 5:d->c 6:c->c 7:m->m
  const int src_t[8] = {0, 1, 0, 1, 2, 2, 0, 1};
  const int dst_t[8] = {1, 2, 2, 0, 1, 0, 0, 1};
  // relations per dst type (3rd used only in layer 3 for T=0,1)
  const int relT[3][3] = {{3, 5, 6}, {0, 4, 7}, {1, 2, -1}};

  int coff[8]; int cntN = 0;
  for (int r = 0; r < 8; ++r) { coff[r] = cntN; cntN += nn[dst_t[r]]; }
  int Etot = 0; for (int r = 0; r < 8; ++r) Etot += E[r];

  // ---- workspace carve (~60 MB; round-5 proved ws_size >= ~73 MB) ----
  char* base = (char*)d_ws;
  int* flag = (int*)base; base += 16;
  __hip_bfloat16* wr[3];
  for (int t = 0; t < 3; ++t) { wr[t] = (__hip_bfloat16*)base; base += 64 * 128 * 2; }
  float* bs[3]; for (int t = 0; t < 3; ++t) { bs[t] = (float*)base; base += 64 * 4; }
  __hip_bfloat16* y = (__hip_bfloat16*)base; base += (size_t)175000 * 64 * 2;  // max rows/phase
  int* degcur = (int*)base; base += (size_t)cntN * 4;
  int* rowptr = (int*)base; base += (size_t)(cntN + 1) * 4;
  int* part = (int*)base; base += (size_t)(DIV_UP(cntN, 256) + 1) * 4;
  int* col = (int*)base; base += (size_t)Etot * 4;
  __hip_bfloat16* h2 = (__hip_bfloat16*)base; base += (size_t)175000 * 64 * 2;
  __hip_bfloat16* h1 = (__hip_bfloat16*)d_out;  // prefix of d_out; dead before layer-3 writes
  (void)n_in; (void)out_size; (void)ws_size;

  detect_dtype<<<1, 256, 0, stream>>>((const unsigned int*)d_in[0], flag);

  // ---- CSR build (edges fixed; shared by all layers) ----
  hipMemsetAsync(degcur, 0, (size_t)cntN * sizeof(int), stream);
  for (int r = 0; r < 8; ++r)
    count_int<<<DIV_UP(E[r], 256), 256, 0, stream>>>(eptr[r] + E[r], degcur + coff[r], E[r]);
  int nb = DIV_UP(cntN, 256);
  scan1<<<nb, 256, 0, stream>>>(degcur, rowptr, part, cntN);
  scan2<<<1, 256, 0, stream>>>(part, nb, rowptr + cntN);
  scan3<<<nb, 256, 0, stream>>>(rowptr, part, cntN);
  copy_int<<<nb, 256, 0, stream>>>(rowptr, degcur, cntN);  // degcur -> cursor
  for (int r = 0; r < 8; ++r)
    fill_csr<<<DIV_UP(E[r], 256), 256, 0, stream>>>(eptr[r], eptr[r] + E[r],
                                                    degcur + coff[r], col, E[r]);

  for (int layer = 0; layer < 3; ++layer) {
    const void* Wl = Wls[layer];
    const void* Wr = Wrs[layer];
    const void* Bb = Bbs[layer];
    const int K = (layer == 0) ? 128 : 64;
    const int wsz = 64 * K;
    const __hip_bfloat16* hin = (layer == 1) ? h1 : h2;  // layer 0 uses X

    for (int T = 0; T < 3; ++T) {
      const int nrel = (layer == 2 && T < 2) ? 3 : 2;
      const int r0 = relT[T][0], r1 = relT[T][1];
      const int r2 = (nrel == 3) ? relT[T][2] : -1;
      wsum_kernel<<<DIV_UP(wsz, 256), 256, 0, stream>>>(
          Wr, r0 * wsz, r1 * wsz, (r2 >= 0) ? r2 * wsz : -1,
          Bb, r0 * 64, r1 * 64, (r2 >= 0) ? r2 * 64 : -1,
          flag, wr[T], bs[T], wsz);
      // y GEMMs for this dst type's relations
      size_t yoffs[3] = {0, 0, 0};
      size_t yoff = 0;
      for (int j = 0; j < nrel; ++j) {
        int r = relT[T][j], st = src_t[r];
        yoffs[j] = yoff;
        if (layer == 0)
          gemm_mfma<128><<<DIV_UP(nn[st], 64), 256, 0, stream>>>(
              X[st], 2, Wl, r * wsz, 2, flag, y + yoff, nn[st]);
        else
          gemm_mfma<64><<<DIV_UP(nn[st], 64), 256, 0, stream>>>(
              hin + toff[st], 1, Wl, r * wsz, 2, flag, y + yoff, nn[st]);
        yoff += (size_t)nn[st] * 64;
      }
      // fused lin_r + gather + epilogue
      const int* rp0 = rowptr + coff[r0];
      const int* rp1 = rowptr + coff[r1];
      const int* rp2 = (r2 >= 0) ? rowptr + coff[r2] : rp0;
      const __hip_bfloat16* y0 = y + yoffs[0];
      const __hip_bfloat16* y1 = y + yoffs[1];
      const __hip_bfloat16* y2 = (r2 >= 0) ? y + yoffs[2] : y0;
      int grid = DIV_UP(nn[T], 16);
      if (layer == 0) {
        fused_agg<128, 0, 2><<<grid, 256, 0, stream>>>(
            X[T], 2, flag, wr[T], bs[T], col, rp0, y0, rp1, y1, rp2, y2,
            0.5f, h1, toff[T], nn[T]);
      } else if (layer == 1) {
        fused_agg<64, 0, 2><<<grid, 256, 0, stream>>>(
            h1 + toff[T], 1, flag, wr[T], bs[T], col, rp0, y0, rp1, y1, rp2, y2,
            0.5f, h2, toff[T], nn[T]);
      } else if (T < 2) {
        fused_agg<64, 1, 3><<<grid, 256, 0, stream>>>(
            h2 + toff[T], 1, flag, wr[T], bs[T], col, rp0, y0, rp1, y1, rp2, y2,
            1.0f / 3.0f, d_out, toff[T], nn[T]);
      } else {
        fused_agg<64, 1, 2><<<grid, 256, 0, stream>>>(
            h2 + toff[T], 1, flag, wr[T], bs[T], col, rp0, y0, rp1, y1, rp2, y2,
            0.5f, d_out, toff[T], nn[T]);
      }
    }
  }
}

// Round 6
// 1069.638 us; speedup vs baseline: 1.3106x; 1.0254x over previous
//
#include <hip/hip_runtime.h>
#include <hip/hip_bf16.h>

#define DIV_UP(a,b) (((a)+(b)-1)/(b))

typedef __bf16 bf16x8 __attribute__((ext_vector_type(8)));
typedef float  f32x4  __attribute__((ext_vector_type(4)));

// ---- runtime dtype detector: bf16 data -> low 16b half of each word has a sane
// bf16 exponent; f32 data -> low half is mantissa garbage. flag=1 means bf16.
__global__ __launch_bounds__(256) void detect_dtype(const unsigned int* __restrict__ x,
                                                    int* __restrict__ flag) {
  __shared__ int cnt_s;
  if (threadIdx.x == 0) cnt_s = 0;
  __syncthreads();
  unsigned w = x[threadIdx.x];
  unsigned lo_exp = (w >> 7) & 0xFF;
  if (lo_exp >= 100 && lo_exp <= 140) atomicAdd(&cnt_s, 1);
  __syncthreads();
  if (threadIdx.x == 0) flag[0] = (cnt_s >= 128) ? 1 : 0;
}

// y[n,64] = x[n,K] @ w[64,K]^T via v_mfma_f32_16x16x32_bf16 (round-5 proven).
// xmode/wmode: 0 = f32 pointer, 1 = bf16 pointer, 2 = dual (use *flagp).
template<int K>
__global__ __launch_bounds__(256) void gemm_mfma(
    const void* __restrict__ x, int xmode,
    const void* __restrict__ w, int woff, int wmode,
    const int* __restrict__ flagp, __hip_bfloat16* __restrict__ out, int n) {
  constexpr int KP = K + 8;
  __shared__ __bf16 xs[64 * KP];
  const bool xb = (xmode == 2) ? (*flagp != 0) : (xmode == 1);
  const bool wb = (wmode == 2) ? (*flagp != 0) : (wmode == 1);
  const int t = threadIdx.x;
  const int wv = t >> 6;
  const int L = t & 63;
  const int m = L & 15, q = L >> 4;
  const int row0 = blockIdx.x * 64;
  const int col = wv * 16 + m;

  bf16x8 bfr[K / 32];
  if (wb) {
    const __bf16* wh = (const __bf16*)w + woff;
#pragma unroll
    for (int ks = 0; ks < K / 32; ++ks)
      bfr[ks] = *(const bf16x8*)&wh[col * K + ks * 32 + q * 8];
  } else {
    const float* wf = (const float*)w + woff;
#pragma unroll
    for (int ks = 0; ks < K / 32; ++ks) {
      bf16x8 b;
#pragma unroll
      for (int j = 0; j < 8; ++j) b[j] = (__bf16)wf[col * K + ks * 32 + q * 8 + j];
      bfr[ks] = b;
    }
  }

  constexpr int CH = K / 8;
  if (xb) {
    const __bf16* xh = (const __bf16*)x;
    for (int idx = t; idx < 64 * CH; idx += 256) {
      int r = idx / CH, c = idx % CH;
      int gr = row0 + r; gr = (gr < n) ? gr : (n - 1);
      *(bf16x8*)&xs[r * KP + c * 8] = *(const bf16x8*)&xh[(size_t)gr * K + c * 8];
    }
  } else {
    const float* xf = (const float*)x;
    for (int idx = t; idx < 64 * CH; idx += 256) {
      int r = idx / CH, c = idx % CH;
      int gr = row0 + r; gr = (gr < n) ? gr : (n - 1);
      const float* src = &xf[(size_t)gr * K + c * 8];
      bf16x8 v;
#pragma unroll
      for (int j = 0; j < 8; ++j) v[j] = (__bf16)src[j];
      *(bf16x8*)&xs[r * KP + c * 8] = v;
    }
  }
  __syncthreads();

  f32x4 acc[4] = {};
#pragma unroll
  for (int ks = 0; ks < K / 32; ++ks) {
#pragma unroll
    for (int rt = 0; rt < 4; ++rt) {
      bf16x8 a = *(const bf16x8*)&xs[(rt * 16 + m) * KP + ks * 32 + q * 8];
      acc[rt] = __builtin_amdgcn_mfma_f32_16x16x32_bf16(a, bfr[ks], acc[rt], 0, 0, 0);
    }
  }

#pragma unroll
  for (int rt = 0; rt < 4; ++rt) {
#pragma unroll
    for (int i = 0; i < 4; ++i) {
      int gr = row0 + rt * 16 + q * 4 + i;
      if (gr < n) out[(size_t)gr * 64 + col] = __float2bfloat16(acc[rt][i]);
    }
  }
}

// ======== fused per-(layer, dst-type): lin_r MFMA + row-per-wave multi-relation
// CSR gather + epilogue (relu->h / l2norm->out). Block = 256 (4 waves) per 16 dst
// rows; wave wv owns rows wv*4..wv*4+3. Round-5 structure (2-row x NREL stream
// interleave, saddr addressing, clamp-to-last masked batches) -- unchanged this
// round. Round-6 change is host-side only: 128B-aligned workspace carves so y/h2
// 128B rows stop spanning two cache lines (was the dominant L2-miss multiplier).
template<int K, int MODE, int NREL>  // MODE 0: relu->bf16; MODE 1: l2norm->flag dtype
__global__ __launch_bounds__(256) void fused_agg(
    const void* __restrict__ xdst, int xmode,
    const int* __restrict__ flagp,
    const __hip_bfloat16* __restrict__ wrsum,  // [64][K] bf16 (merged lin_r)
    const float* __restrict__ bias,            // [64] (merged)
    const int* __restrict__ col,               // shared CSR col array
    const int* __restrict__ rp0, const __hip_bfloat16* __restrict__ y0,
    const int* __restrict__ rp1, const __hip_bfloat16* __restrict__ y1,
    const int* __restrict__ rp2, const __hip_bfloat16* __restrict__ y2,
    float invR,
    void* __restrict__ outp, size_t obase, int n) {
  __shared__ float dbuf[16][68];
  __shared__ int rpl_s[NREL][17];   // rowptr[row0..row0+16] per relation
  const bool xb = (xmode == 2) ? (*flagp != 0) : (xmode == 1);
  const int t = threadIdx.x;
  const int wv = t >> 6, L = t & 63;
  const int m = L & 15, q = L >> 4;
  const int row0 = blockIdx.x * 16;
  const int colc = wv * 16 + m;

  // --- cooperative rowptr load (overlaps MFMA latency; existing sync covers it) ---
  if (t < NREL * 17) {
    int j = t / 17, k = t - j * 17;
    const int* rp = (j == 0) ? rp0 : (j == 1) ? rp1 : rp2;
    int gi = row0 + k; gi = (gi < n) ? gi : n;   // rows >= n -> zero-length spans
    rpl_s[j][k] = rp[gi];
  }

  // --- lin_r MFMA: B fragments = this wave's 16 cols of Wr_sum ---
  const __bf16* wh = (const __bf16*)wrsum;
  bf16x8 bfr[K / 32];
#pragma unroll
  for (int ks = 0; ks < K / 32; ++ks)
    bfr[ks] = *(const bf16x8*)&wh[colc * K + ks * 32 + q * 8];

  // A fragments: row (row0+m) of x_dst
  int ar = row0 + m; ar = (ar < n) ? ar : (n - 1);
  f32x4 acc = {};
  if (xb) {
    const __bf16* xp = (const __bf16*)xdst;
#pragma unroll
    for (int ks = 0; ks < K / 32; ++ks) {
      bf16x8 a = *(const bf16x8*)&xp[(size_t)ar * K + ks * 32 + q * 8];
      acc = __builtin_amdgcn_mfma_f32_16x16x32_bf16(a, bfr[ks], acc, 0, 0, 0);
    }
  } else {
    const float* xp = (const float*)xdst;
#pragma unroll
    for (int ks = 0; ks < K / 32; ++ks) {
      bf16x8 a;
#pragma unroll
      for (int j = 0; j < 8; ++j) a[j] = (__bf16)xp[(size_t)ar * K + ks * 32 + q * 8 + j];
      acc = __builtin_amdgcn_mfma_f32_16x16x32_bf16(a, bfr[ks], acc, 0, 0, 0);
    }
  }
  float bc = bias[colc];
#pragma unroll
  for (int i = 0; i < 4; ++i) dbuf[q * 4 + i][colc] = acc[i] + bc;  // D row = q*4+i
  __syncthreads();

  const char* ys[3] = {(const char*)y0, (const char*)y1, (const char*)y2};
  const int jj = L & 31;            // column-pair index: cols 2jj, 2jj+1
  const int half = L >> 5;          // 0: even edge positions; 1: odd
  const unsigned jb = (unsigned)jj << 2;   // byte offset of this lane's pair

#pragma unroll 1
  for (int pass = 0; pass < 2; ++pass) {
    // per-(row u, relation j) stream state; all indices compile-time (rule #20)
    int b0[2][NREL], dg[2][NREL];
    float g0[2][NREL], g1[2][NREL];
    int nbmax = 0;
#pragma unroll
    for (int u = 0; u < 2; ++u) {
      const int lr = wv * 4 + pass * 2 + u;
#pragma unroll
      for (int j = 0; j < NREL; ++j) {
        int s = rpl_s[j][lr], e = rpl_s[j][lr + 1];
        b0[u][j] = s; dg[u][j] = e - s;
        g0[u][j] = 0.0f; g1[u][j] = 0.0f;
        int nbj = (e - s + 3) >> 2;
        nbmax = (nbj > nbmax) ? nbj : nbmax;
      }
    }

#pragma unroll 1
    for (int b = 0; b < nbmax; ++b) {
      const int bb = b << 2;
      unsigned wd[2][NREL][2];
      // phase 1+2: col loads and y loads for every active stream (interleaved
      // issue; up to 2*NREL*2 y lines in flight)
#pragma unroll
      for (int u = 0; u < 2; ++u)
#pragma unroll
        for (int j = 0; j < NREL; ++j) {
          int rem = dg[u][j] - bb;
          if (rem > 0) {                       // wave-uniform guard
            int last = rem - 1;
            int o0 = (half < last) ? half : last;          // clamp: cache-hit repeat
            int o1 = (2 + half < last) ? (2 + half) : last;
            int p = b0[u][j] + bb;
            unsigned c0 = (unsigned)col[p + o0];
            unsigned c1 = (unsigned)col[p + o1];
            wd[u][j][0] = *(const unsigned*)(ys[j] + ((c0 << 7) + jb));
            wd[u][j][1] = *(const unsigned*)(ys[j] + ((c1 << 7) + jb));
          }
        }
      // phase 3: masked accumulate
#pragma unroll
      for (int u = 0; u < 2; ++u)
#pragma unroll
        for (int j = 0; j < NREL; ++j) {
          int rem = dg[u][j] - bb;
          if (rem > 0) {
            unsigned w0 = (half < rem) ? wd[u][j][0] : 0u;
            unsigned w1 = (2 + half < rem) ? wd[u][j][1] : 0u;
            g0[u][j] += __uint_as_float(w0 << 16) + __uint_as_float(w1 << 16);
            g1[u][j] += __uint_as_float(w0 & 0xffff0000u) + __uint_as_float(w1 & 0xffff0000u);
          }
        }
    }

    // epilogue for this pass's 2 rows
#pragma unroll
    for (int u = 0; u < 2; ++u) {
      const int lr = wv * 4 + pass * 2 + u;
      const int gr = row0 + lr;
      if (gr >= n) continue;                   // wave-uniform
      float t0 = 0.0f, t1 = 0.0f;
#pragma unroll
      for (int j = 0; j < NREL; ++j) {
        float idg = (dg[u][j] > 0) ? (1.0f / (float)dg[u][j]) : 0.0f;
        t0 += g0[u][j] * idg; t1 += g1[u][j] * idg;
      }
      t0 += __shfl_xor(t0, 32, 64);            // merge even/odd halves
      t1 += __shfl_xor(t1, 32, 64);
      float2 d2 = *(const float2*)&dbuf[lr][2 * jj];
      float s0 = (d2.x + t0) * invR;
      float s1 = (d2.y + t1) * invR;

      if (MODE == 0) {
        if (half == 0) {
          __hip_bfloat16 b0v = __float2bfloat16(fmaxf(s0, 0.0f));
          __hip_bfloat16 b1v = __float2bfloat16(fmaxf(s1, 0.0f));
          unsigned pw = ((unsigned)*(const unsigned short*)&b1v << 16) |
                        (unsigned)*(const unsigned short*)&b0v;
          *(unsigned*)((__hip_bfloat16*)outp + obase + (size_t)gr * 64 + 2 * jj) = pw;
        }
      } else {
        float ss = s0 * s0 + s1 * s1;
#pragma unroll
        for (int o = 16; o > 0; o >>= 1) ss += __shfl_xor(ss, o, 64);  // full 64-col sum per half
        float sc = 1.0f / fmaxf(sqrtf(ss), 1e-12f);
        float r0 = s0 * sc, r1 = s1 * sc;
        if (half == 0) {
          size_t idx = obase + (size_t)gr * 64 + 2 * jj;
          if (*flagp) {
            __hip_bfloat16 b0v = __float2bfloat16(r0);
            __hip_bfloat16 b1v = __float2bfloat16(r1);
            unsigned pw = ((unsigned)*(const unsigned short*)&b1v << 16) |
                          (unsigned)*(const unsigned short*)&b0v;
            *(unsigned*)((__hip_bfloat16*)outp + idx) = pw;
          } else {
            float2 v; v.x = r0; v.y = r1;
            *(float2*)((float*)outp + idx) = v;
          }
        }
      }
    }
  }
}

// ======== CSR build (round-4 proven) ========
__global__ __launch_bounds__(256) void count_int(const int* __restrict__ ed,
                                                 int* __restrict__ deg, int E) {
  int i = blockIdx.x * 256 + threadIdx.x;
  if (i < E) atomicAdd(&deg[ed[i]], 1);
}

__global__ __launch_bounds__(256) void scan1(const int* __restrict__ deg,
    int* __restrict__ outp, int* __restrict__ part, int n) {
  __shared__ int tmp[256];
  int gid = blockIdx.x * 256 + threadIdx.x;
  int v = (gid < n) ? deg[gid] : 0;
  tmp[threadIdx.x] = v;
  __syncthreads();
  for (int off = 1; off < 256; off <<= 1) {
    int t = (threadIdx.x >= off) ? tmp[threadIdx.x - off] : 0;
    __syncthreads();
    tmp[threadIdx.x] += t;
    __syncthreads();
  }
  if (gid < n) outp[gid] = tmp[threadIdx.x] - v;  // exclusive
  if (threadIdx.x == 255) part[blockIdx.x] = tmp[255];
}

__global__ __launch_bounds__(256) void scan2(int* __restrict__ part, int P,
                                             int* __restrict__ totalout) {
  __shared__ int tmp[256];
  __shared__ int carry;
  if (threadIdx.x == 0) carry = 0;
  __syncthreads();
  for (int base0 = 0; base0 < P; base0 += 256) {
    int i = base0 + threadIdx.x;
    int v = (i < P) ? part[i] : 0;
    tmp[threadIdx.x] = v;
    __syncthreads();
    for (int off = 1; off < 256; off <<= 1) {
      int t = (threadIdx.x >= off) ? tmp[threadIdx.x - off] : 0;
      __syncthreads();
      tmp[threadIdx.x] += t;
      __syncthreads();
    }
    if (i < P) part[i] = tmp[threadIdx.x] - v + carry;
    __syncthreads();
    if (threadIdx.x == 0) carry += tmp[255];
    __syncthreads();
  }
  if (threadIdx.x == 0) *totalout = carry;
}

__global__ __launch_bounds__(256) void scan3(int* __restrict__ outp,
    const int* __restrict__ part, int n) {
  int gid = blockIdx.x * 256 + threadIdx.x;
  if (gid < n) outp[gid] += part[blockIdx.x];
}

__global__ __launch_bounds__(256) void copy_int(const int* __restrict__ src,
                                                int* __restrict__ dst, int n) {
  int i = blockIdx.x * 256 + threadIdx.x;
  if (i < n) dst[i] = src[i];
}

__global__ __launch_bounds__(256) void fill_csr(const int* __restrict__ es,
    const int* __restrict__ ed, int* __restrict__ cursor, int* __restrict__ col, int E) {
  int i = blockIdx.x * 256 + threadIdx.x;
  if (i < E) {
    int pos = atomicAdd(&cursor[ed[i]], 1);
    col[pos] = es[i];
  }
}

// wout(bf16) = W[o0] + W[o1] (+ W[o2]); bout(f32) similarly; offsets in elements
__global__ __launch_bounds__(256) void wsum_kernel(
    const void* __restrict__ W, int o0, int o1, int o2,
    const void* __restrict__ B, int p0, int p1, int p2,
    const int* __restrict__ flagp, __hip_bfloat16* __restrict__ wout,
    float* __restrict__ bout, int wsz) {
  const bool bf = (*flagp != 0);
  int i = blockIdx.x * 256 + threadIdx.x;
  float s = 0.0f, sb = 0.0f;
  if (bf) {
    const __hip_bfloat16* Wp = (const __hip_bfloat16*)W;
    const __hip_bfloat16* Bp = (const __hip_bfloat16*)B;
    if (i < wsz) {
      s = __bfloat162float(Wp[o0 + i]) + __bfloat162float(Wp[o1 + i]);
      if (o2 >= 0) s += __bfloat162float(Wp[o2 + i]);
    }
    if (i < 64) {
      sb = __bfloat162float(Bp[p0 + i]) + __bfloat162float(Bp[p1 + i]);
      if (p2 >= 0) sb += __bfloat162float(Bp[p2 + i]);
    }
  } else {
    const float* Wp = (const float*)W;
    const float* Bp = (const float*)B;
    if (i < wsz) {
      s = Wp[o0 + i] + Wp[o1 + i];
      if (o2 >= 0) s += Wp[o2 + i];
    }
    if (i < 64) {
      sb = Bp[p0 + i] + Bp[p1 + i];
      if (p2 >= 0) sb += Bp[p2 + i];
    }
  }
  if (i < wsz) wout[i] = __float2bfloat16(s);
  if (i < 64) bout[i] = sb;
}

extern "C" void kernel_launch(void* const* d_in, const int* in_sizes, int n_in,
                              void* d_out, int out_size, void* d_ws, size_t ws_size,
                              hipStream_t stream) {
  const int NC = 100000, NM = 50000, ND = 25000;
  const int nn[3] = {NC, NM, ND};
  const size_t toff[3] = {0, (size_t)NC * 64, (size_t)(NC + NM) * 64};
  const void* X[3] = {d_in[0], d_in[1], d_in[2]};
  const int* eptr[8]; int E[8];
  for (int r = 0; r < 8; ++r) { eptr[r] = (const int*)d_in[3 + r]; E[r] = in_sizes[3 + r] / 2; }
  const void* Wls[3] = {d_in[11], d_in[14], d_in[17]};
  const void* Wrs[3] = {d_in[12], d_in[15], d_in[18]};
  const void* Bbs[3] = {d_in[13], d_in[16], d_in[19]};

  // relation r: 0:c->m 1:m->d 2:c->d 3:m->c 4:d->m 5:d->c 6:c->c 7:m->m
  const int src_t[8] = {0, 1, 0, 1, 2, 2, 0, 1};
  const int dst_t[8] = {1, 2, 2, 0, 1, 0, 0, 1};
  // relations per dst type (3rd used only in layer 3 for T=0,1)
  const int relT[3][3] = {{3, 5, 6}, {0, 4, 7}, {1, 2, -1}};

  int coff[8]; int cntN = 0;
  for (int r = 0; r < 8; ++r) { coff[r] = cntN; cntN += nn[dst_t[r]]; }
  int Etot = 0; for (int r = 0; r < 8; ++r) Etot += E[r];

  // ---- workspace carve (~60 MB; round-5 proved ws_size >= ~73 MB) ----
  // Round-6: every carve 128B-aligned. Critical: y and h2 hold 128B rows that are
  // randomly gathered; pre-fix they sat at +16B / +64B off 128B lines, so EVERY
  // row access touched two cache lines (2x L2 miss-path requests on the dominant
  // traffic stream) and every GEMM row-write was two partial-line writes.
  char* base = (char*)d_ws;
  auto carve = [&](size_t bytes) -> char* {
    char* p = (char*)(((uintptr_t)base + 127) & ~(uintptr_t)127);
    base = p + bytes;
    return p;
  };
  int* flag = (int*)carve(16);
  __hip_bfloat16* wr[3];
  for (int t = 0; t < 3; ++t) wr[t] = (__hip_bfloat16*)carve(64 * 128 * 2);
  float* bs[3]; for (int t = 0; t < 3; ++t) bs[t] = (float*)carve(64 * 4);
  __hip_bfloat16* y = (__hip_bfloat16*)carve((size_t)175000 * 64 * 2);  // max rows/phase
  int* degcur = (int*)carve((size_t)cntN * 4);
  int* rowptr = (int*)carve((size_t)(cntN + 1) * 4);
  int* part = (int*)carve((size_t)(DIV_UP(cntN, 256) + 1) * 4);
  int* col = (int*)carve((size_t)Etot * 4);
  __hip_bfloat16* h2 = (__hip_bfloat16*)carve((size_t)175000 * 64 * 2);
  __hip_bfloat16* h1 = (__hip_bfloat16*)d_out;  // prefix of d_out; dead before layer-3 writes
  (void)n_in; (void)out_size; (void)ws_size;

  detect_dtype<<<1, 256, 0, stream>>>((const unsigned int*)d_in[0], flag);

  // ---- CSR build (edges fixed; shared by all layers) ----
  hipMemsetAsync(degcur, 0, (size_t)cntN * sizeof(int), stream);
  for (int r = 0; r < 8; ++r)
    count_int<<<DIV_UP(E[r], 256), 256, 0, stream>>>(eptr[r] + E[r], degcur + coff[r], E[r]);
  int nb = DIV_UP(cntN, 256);
  scan1<<<nb, 256, 0, stream>>>(degcur, rowptr, part, cntN);
  scan2<<<1, 256, 0, stream>>>(part, nb, rowptr + cntN);
  scan3<<<nb, 256, 0, stream>>>(rowptr, part, cntN);
  copy_int<<<nb, 256, 0, stream>>>(rowptr, degcur, cntN);  // degcur -> cursor
  for (int r = 0; r < 8; ++r)
    fill_csr<<<DIV_UP(E[r], 256), 256, 0, stream>>>(eptr[r], eptr[r] + E[r],
                                                    degcur + coff[r], col, E[r]);

  for (int layer = 0; layer < 3; ++layer) {
    const void* Wl = Wls[layer];
    const void* Wr = Wrs[layer];
    const void* Bb = Bbs[layer];
    const int K = (layer == 0) ? 128 : 64;
    const int wsz = 64 * K;
    const __hip_bfloat16* hin = (layer == 1) ? h1 : h2;  // layer 0 uses X

    for (int T = 0; T < 3; ++T) {
      const int nrel = (layer == 2 && T < 2) ? 3 : 2;
      const int r0 = relT[T][0], r1 = relT[T][1];
      const int r2 = (nrel == 3) ? relT[T][2] : -1;
      wsum_kernel<<<DIV_UP(wsz, 256), 256, 0, stream>>>(
          Wr, r0 * wsz, r1 * wsz, (r2 >= 0) ? r2 * wsz : -1,
          Bb, r0 * 64, r1 * 64, (r2 >= 0) ? r2 * 64 : -1,
          flag, wr[T], bs[T], wsz);
      // y GEMMs for this dst type's relations
      size_t yoffs[3] = {0, 0, 0};
      size_t yoff = 0;
      for (int j = 0; j < nrel; ++j) {
        int r = relT[T][j], st = src_t[r];
        yoffs[j] = yoff;
        if (layer == 0)
          gemm_mfma<128><<<DIV_UP(nn[st], 64), 256, 0, stream>>>(
              X[st], 2, Wl, r * wsz, 2, flag, y + yoff, nn[st]);
        else
          gemm_mfma<64><<<DIV_UP(nn[st], 64), 256, 0, stream>>>(
              hin + toff[st], 1, Wl, r * wsz, 2, flag, y + yoff, nn[st]);
        yoff += (size_t)nn[st] * 64;
      }
      // fused lin_r + gather + epilogue
      const int* rp0 = rowptr + coff[r0];
      const int* rp1 = rowptr + coff[r1];
      const int* rp2 = (r2 >= 0) ? rowptr + coff[r2] : rp0;
      const __hip_bfloat16* y0 = y + yoffs[0];
      const __hip_bfloat16* y1 = y + yoffs[1];
      const __hip_bfloat16* y2 = (r2 >= 0) ? y + yoffs[2] : y0;
      int grid = DIV_UP(nn[T], 16);
      if (layer == 0) {
        fused_agg<128, 0, 2><<<grid, 256, 0, stream>>>(
            X[T], 2, flag, wr[T], bs[T], col, rp0, y0, rp1, y1, rp2, y2,
            0.5f, h1, toff[T], nn[T]);
      } else if (layer == 1) {
        fused_agg<64, 0, 2><<<grid, 256, 0, stream>>>(
            h1 + toff[T], 1, flag, wr[T], bs[T], col, rp0, y0, rp1, y1, rp2, y2,
            0.5f, h2, toff[T], nn[T]);
      } else if (T < 2) {
        fused_agg<64, 1, 3><<<grid, 256, 0, stream>>>(
            h2 + toff[T], 1, flag, wr[T], bs[T], col, rp0, y0, rp1, y1, rp2, y2,
            1.0f / 3.0f, d_out, toff[T], nn[T]);
      } else {
        fused_agg<64, 1, 2><<<grid, 256, 0, stream>>>(
            h2 + toff[T], 1, flag, wr[T], bs[T], col, rp0, y0, rp1, y1, rp2, y2,
            0.5f, d_out, toff[T], nn[T]);
      }
    }
  }
}

// Round 7
// 1035.374 us; speedup vs baseline: 1.3540x; 1.0331x over previous
//
#include <hip/hip_runtime.h>
#include <hip/hip_bf16.h>

#define DIV_UP(a,b) (((a)+(b)-1)/(b))

typedef __bf16 bf16x8 __attribute__((ext_vector_type(8)));
typedef float  f32x4  __attribute__((ext_vector_type(4)));

// ---- runtime dtype detector: bf16 data -> low 16b half of each word has a sane
// bf16 exponent; f32 data -> low half is mantissa garbage. flag=1 means bf16.
__global__ __launch_bounds__(256) void detect_dtype(const unsigned int* __restrict__ x,
                                                    int* __restrict__ flag) {
  __shared__ int cnt_s;
  if (threadIdx.x == 0) cnt_s = 0;
  __syncthreads();
  unsigned w = x[threadIdx.x];
  unsigned lo_exp = (w >> 7) & 0xFF;
  if (lo_exp >= 100 && lo_exp <= 140) atomicAdd(&cnt_s, 1);
  __syncthreads();
  if (threadIdx.x == 0) flag[0] = (cnt_s >= 128) ? 1 : 0;
}

// y[n,64] = x[n,K] @ w[64,K]^T via v_mfma_f32_16x16x32_bf16 (round-5 proven).
// xmode/wmode: 0 = f32 pointer, 1 = bf16 pointer, 2 = dual (use *flagp).
template<int K>
__global__ __launch_bounds__(256) void gemm_mfma(
    const void* __restrict__ x, int xmode,
    const void* __restrict__ w, int woff, int wmode,
    const int* __restrict__ flagp, __hip_bfloat16* __restrict__ out, int n) {
  constexpr int KP = K + 8;
  __shared__ __bf16 xs[64 * KP];
  const bool xb = (xmode == 2) ? (*flagp != 0) : (xmode == 1);
  const bool wb = (wmode == 2) ? (*flagp != 0) : (wmode == 1);
  const int t = threadIdx.x;
  const int wv = t >> 6;
  const int L = t & 63;
  const int m = L & 15, q = L >> 4;
  const int row0 = blockIdx.x * 64;
  const int col = wv * 16 + m;

  bf16x8 bfr[K / 32];
  if (wb) {
    const __bf16* wh = (const __bf16*)w + woff;
#pragma unroll
    for (int ks = 0; ks < K / 32; ++ks)
      bfr[ks] = *(const bf16x8*)&wh[col * K + ks * 32 + q * 8];
  } else {
    const float* wf = (const float*)w + woff;
#pragma unroll
    for (int ks = 0; ks < K / 32; ++ks) {
      bf16x8 b;
#pragma unroll
      for (int j = 0; j < 8; ++j) b[j] = (__bf16)wf[col * K + ks * 32 + q * 8 + j];
      bfr[ks] = b;
    }
  }

  constexpr int CH = K / 8;
  if (xb) {
    const __bf16* xh = (const __bf16*)x;
    for (int idx = t; idx < 64 * CH; idx += 256) {
      int r = idx / CH, c = idx % CH;
      int gr = row0 + r; gr = (gr < n) ? gr : (n - 1);
      *(bf16x8*)&xs[r * KP + c * 8] = *(const bf16x8*)&xh[(size_t)gr * K + c * 8];
    }
  } else {
    const float* xf = (const float*)x;
    for (int idx = t; idx < 64 * CH; idx += 256) {
      int r = idx / CH, c = idx % CH;
      int gr = row0 + r; gr = (gr < n) ? gr : (n - 1);
      const float* src = &xf[(size_t)gr * K + c * 8];
      bf16x8 v;
#pragma unroll
      for (int j = 0; j < 8; ++j) v[j] = (__bf16)src[j];
      *(bf16x8*)&xs[r * KP + c * 8] = v;
    }
  }
  __syncthreads();

  f32x4 acc[4] = {};
#pragma unroll
  for (int ks = 0; ks < K / 32; ++ks) {
#pragma unroll
    for (int rt = 0; rt < 4; ++rt) {
      bf16x8 a = *(const bf16x8*)&xs[(rt * 16 + m) * KP + ks * 32 + q * 8];
      acc[rt] = __builtin_amdgcn_mfma_f32_16x16x32_bf16(a, bfr[ks], acc[rt], 0, 0, 0);
    }
  }

#pragma unroll
  for (int rt = 0; rt < 4; ++rt) {
#pragma unroll
    for (int i = 0; i < 4; ++i) {
      int gr = row0 + rt * 16 + q * 4 + i;
      if (gr < n) out[(size_t)gr * 64 + col] = __float2bfloat16(acc[rt][i]);
    }
  }
}

// ======== fused per-(layer, dst-type): lin_r MFMA + row-per-wave multi-relation
// CSR gather + epilogue (relu->h / l2norm->out). Block = 256 (4 waves) per 16 dst
// rows; wave wv owns rows wv*4..wv*4+3. Round-5/6 gather structure (2-row x NREL
// interleave, clamp-to-last masked batches, 128B-aligned y) unchanged.
// Round-7: cooperative LDS col staging. A block's 16 rows are contiguous in CSR,
// so each relation's col indices are ONE contiguous span (mean 80-200/block).
// Stage spans into cbuf BEFORE the MFMA phase (staging latency hides under the
// MFMA phase's loads; existing barrier covers it). The gather batch then reads
// col indices via broadcast ds_read (~60cy) instead of a ~200cy global round trip
// -> one memory epoch per batch instead of two (the measured latency bottleneck).
// Block-uniform fallback to global col reads if span > CAP (=512, ~30 sigma).
template<int K, int MODE, int NREL>  // MODE 0: relu->bf16; MODE 1: l2norm->flag dtype
__global__ __launch_bounds__(256) void fused_agg(
    const void* __restrict__ xdst, int xmode,
    const int* __restrict__ flagp,
    const __hip_bfloat16* __restrict__ wrsum,  // [64][K] bf16 (merged lin_r)
    const float* __restrict__ bias,            // [64] (merged)
    const int* __restrict__ col,               // shared CSR col array
    const int* __restrict__ rp0, const __hip_bfloat16* __restrict__ y0,
    const int* __restrict__ rp1, const __hip_bfloat16* __restrict__ y1,
    const int* __restrict__ rp2, const __hip_bfloat16* __restrict__ y2,
    float invR,
    void* __restrict__ outp, size_t obase, int n) {
  constexpr int CAP = 512;
  __shared__ float dbuf[16][68];
  __shared__ int rpl_s[NREL][17];   // rowptr[row0..row0+16] per relation
  __shared__ int cbuf[NREL][CAP];   // staged col spans (one contiguous span/rel)
  const bool xb = (xmode == 2) ? (*flagp != 0) : (xmode == 1);
  const int t = threadIdx.x;
  const int wv = t >> 6, L = t & 63;
  const int m = L & 15, q = L >> 4;
  const int row0 = blockIdx.x * 16;
  const int colc = wv * 16 + m;

  // --- uniform span bounds (SGPR loads) + cooperative col staging, issued FIRST
  // so the staging global loads overlap the whole MFMA phase ---
  const int* rps[3] = {rp0, rp1, rp2};
  int hi16 = row0 + 16; hi16 = (hi16 < n) ? hi16 : n;
  int sj[NREL]; bool fit[NREL];
#pragma unroll
  for (int j = 0; j < NREL; ++j) {
    sj[j] = rps[j][row0];
    int span = rps[j][hi16] - sj[j];
    fit[j] = (span <= CAP);
    int lim = fit[j] ? span : 0;          // skip staging on overflow
    for (int i = t; i < lim; i += 256) cbuf[j][i] = col[sj[j] + i];
  }

  // --- cooperative rowptr load (overlaps MFMA latency; existing sync covers it) ---
  if (t < NREL * 17) {
    int j = t / 17, k = t - j * 17;
    const int* rp = (j == 0) ? rp0 : (j == 1) ? rp1 : rp2;
    int gi = row0 + k; gi = (gi < n) ? gi : n;   // rows >= n -> zero-length spans
    rpl_s[j][k] = rp[gi];
  }

  // --- lin_r MFMA: B fragments = this wave's 16 cols of Wr_sum ---
  const __bf16* wh = (const __bf16*)wrsum;
  bf16x8 bfr[K / 32];
#pragma unroll
  for (int ks = 0; ks < K / 32; ++ks)
    bfr[ks] = *(const bf16x8*)&wh[colc * K + ks * 32 + q * 8];

  // A fragments: row (row0+m) of x_dst
  int ar = row0 + m; ar = (ar < n) ? ar : (n - 1);
  f32x4 acc = {};
  if (xb) {
    const __bf16* xp = (const __bf16*)xdst;
#pragma unroll
    for (int ks = 0; ks < K / 32; ++ks) {
      bf16x8 a = *(const bf16x8*)&xp[(size_t)ar * K + ks * 32 + q * 8];
      acc = __builtin_amdgcn_mfma_f32_16x16x32_bf16(a, bfr[ks], acc, 0, 0, 0);
    }
  } else {
    const float* xp = (const float*)xdst;
#pragma unroll
    for (int ks = 0; ks < K / 32; ++ks) {
      bf16x8 a;
#pragma unroll
      for (int j = 0; j < 8; ++j) a[j] = (__bf16)xp[(size_t)ar * K + ks * 32 + q * 8 + j];
      acc = __builtin_amdgcn_mfma_f32_16x16x32_bf16(a, bfr[ks], acc, 0, 0, 0);
    }
  }
  float bc = bias[colc];
#pragma unroll
  for (int i = 0; i < 4; ++i) dbuf[q * 4 + i][colc] = acc[i] + bc;  // D row = q*4+i
  __syncthreads();   // covers dbuf, rpl_s, cbuf

  const char* ys[3] = {(const char*)y0, (const char*)y1, (const char*)y2};
  const int jj = L & 31;            // column-pair index: cols 2jj, 2jj+1
  const int half = L >> 5;          // 0: even edge positions; 1: odd
  const unsigned jb = (unsigned)jj << 2;   // byte offset of this lane's pair

#pragma unroll 1
  for (int pass = 0; pass < 2; ++pass) {
    // per-(row u, relation j) stream state; all indices compile-time (rule #20)
    int b0[2][NREL], dg[2][NREL];
    float g0[2][NREL], g1[2][NREL];
    int nbmax = 0;
#pragma unroll
    for (int u = 0; u < 2; ++u) {
      const int lr = wv * 4 + pass * 2 + u;
#pragma unroll
      for (int j = 0; j < NREL; ++j) {
        int s = rpl_s[j][lr], e = rpl_s[j][lr + 1];
        b0[u][j] = s; dg[u][j] = e - s;
        g0[u][j] = 0.0f; g1[u][j] = 0.0f;
        int nbj = (e - s + 3) >> 2;
        nbmax = (nbj > nbmax) ? nbj : nbmax;
      }
    }

#pragma unroll 1
    for (int b = 0; b < nbmax; ++b) {
      const int bb = b << 2;
      unsigned wd[2][NREL][2];
      // phase 1+2: col indices from LDS (broadcast ds_read, ~60cy) then y loads
      // for every active stream (up to 2*NREL*2 y lines in flight)
#pragma unroll
      for (int u = 0; u < 2; ++u)
#pragma unroll
        for (int j = 0; j < NREL; ++j) {
          int rem = dg[u][j] - bb;
          if (rem > 0) {                       // wave-uniform guard
            int last = rem - 1;
            int o0 = (half < last) ? half : last;          // clamp: cache-hit repeat
            int o1 = (2 + half < last) ? (2 + half) : last;
            unsigned c0, c1;
            if (fit[j]) {                      // block-uniform branch
              int lp = b0[u][j] - sj[j] + bb;
              c0 = (unsigned)cbuf[j][lp + o0];
              c1 = (unsigned)cbuf[j][lp + o1];
            } else {
              int p = b0[u][j] + bb;
              c0 = (unsigned)col[p + o0];
              c1 = (unsigned)col[p + o1];
            }
            wd[u][j][0] = *(const unsigned*)(ys[j] + ((c0 << 7) + jb));
            wd[u][j][1] = *(const unsigned*)(ys[j] + ((c1 << 7) + jb));
          }
        }
      // phase 3: masked accumulate
#pragma unroll
      for (int u = 0; u < 2; ++u)
#pragma unroll
        for (int j = 0; j < NREL; ++j) {
          int rem = dg[u][j] - bb;
          if (rem > 0) {
            unsigned w0 = (half < rem) ? wd[u][j][0] : 0u;
            unsigned w1 = (2 + half < rem) ? wd[u][j][1] : 0u;
            g0[u][j] += __uint_as_float(w0 << 16) + __uint_as_float(w1 << 16);
            g1[u][j] += __uint_as_float(w0 & 0xffff0000u) + __uint_as_float(w1 & 0xffff0000u);
          }
        }
    }

    // epilogue for this pass's 2 rows
#pragma unroll
    for (int u = 0; u < 2; ++u) {
      const int lr = wv * 4 + pass * 2 + u;
      const int gr = row0 + lr;
      if (gr >= n) continue;                   // wave-uniform
      float t0 = 0.0f, t1 = 0.0f;
#pragma unroll
      for (int j = 0; j < NREL; ++j) {
        float idg = (dg[u][j] > 0) ? (1.0f / (float)dg[u][j]) : 0.0f;
        t0 += g0[u][j] * idg; t1 += g1[u][j] * idg;
      }
      t0 += __shfl_xor(t0, 32, 64);            // merge even/odd halves
      t1 += __shfl_xor(t1, 32, 64);
      float2 d2 = *(const float2*)&dbuf[lr][2 * jj];
      float s0 = (d2.x + t0) * invR;
      float s1 = (d2.y + t1) * invR;

      if (MODE == 0) {
        if (half == 0) {
          __hip_bfloat16 b0v = __float2bfloat16(fmaxf(s0, 0.0f));
          __hip_bfloat16 b1v = __float2bfloat16(fmaxf(s1, 0.0f));
          unsigned pw = ((unsigned)*(const unsigned short*)&b1v << 16) |
                        (unsigned)*(const unsigned short*)&b0v;
          *(unsigned*)((__hip_bfloat16*)outp + obase + (size_t)gr * 64 + 2 * jj) = pw;
        }
      } else {
        float ss = s0 * s0 + s1 * s1;
#pragma unroll
        for (int o = 16; o > 0; o >>= 1) ss += __shfl_xor(ss, o, 64);  // full 64-col sum per half
        float sc = 1.0f / fmaxf(sqrtf(ss), 1e-12f);
        float r0 = s0 * sc, r1 = s1 * sc;
        if (half == 0) {
          size_t idx = obase + (size_t)gr * 64 + 2 * jj;
          if (*flagp) {
            __hip_bfloat16 b0v = __float2bfloat16(r0);
            __hip_bfloat16 b1v = __float2bfloat16(r1);
            unsigned pw = ((unsigned)*(const unsigned short*)&b1v << 16) |
                          (unsigned)*(const unsigned short*)&b0v;
            *(unsigned*)((__hip_bfloat16*)outp + idx) = pw;
          } else {
            float2 v; v.x = r0; v.y = r1;
            *(float2*)((float*)outp + idx) = v;
          }
        }
      }
    }
  }
}

// ======== CSR build (round-4 proven) ========
__global__ __launch_bounds__(256) void count_int(const int* __restrict__ ed,
                                                 int* __restrict__ deg, int E) {
  int i = blockIdx.x * 256 + threadIdx.x;
  if (i < E) atomicAdd(&deg[ed[i]], 1);
}

__global__ __launch_bounds__(256) void scan1(const int* __restrict__ deg,
    int* __restrict__ outp, int* __restrict__ part, int n) {
  __shared__ int tmp[256];
  int gid = blockIdx.x * 256 + threadIdx.x;
  int v = (gid < n) ? deg[gid] : 0;
  tmp[threadIdx.x] = v;
  __syncthreads();
  for (int off = 1; off < 256; off <<= 1) {
    int t = (threadIdx.x >= off) ? tmp[threadIdx.x - off] : 0;
    __syncthreads();
    tmp[threadIdx.x] += t;
    __syncthreads();
  }
  if (gid < n) outp[gid] = tmp[threadIdx.x] - v;  // exclusive
  if (threadIdx.x == 255) part[blockIdx.x] = tmp[255];
}

__global__ __launch_bounds__(256) void scan2(int* __restrict__ part, int P,
                                             int* __restrict__ totalout) {
  __shared__ int tmp[256];
  __shared__ int carry;
  if (threadIdx.x == 0) carry = 0;
  __syncthreads();
  for (int base0 = 0; base0 < P; base0 += 256) {
    int i = base0 + threadIdx.x;
    int v = (i < P) ? part[i] : 0;
    tmp[threadIdx.x] = v;
    __syncthreads();
    for (int off = 1; off < 256; off <<= 1) {
      int t = (threadIdx.x >= off) ? tmp[threadIdx.x - off] : 0;
      __syncthreads();
      tmp[threadIdx.x] += t;
      __syncthreads();
    }
    if (i < P) part[i] = tmp[threadIdx.x] - v + carry;
    __syncthreads();
    if (threadIdx.x == 0) carry += tmp[255];
    __syncthreads();
  }
  if (threadIdx.x == 0) *totalout = carry;
}

__global__ __launch_bounds__(256) void scan3(int* __restrict__ outp,
    const int* __restrict__ part, int n) {
  int gid = blockIdx.x * 256 + threadIdx.x;
  if (gid < n) outp[gid] += part[blockIdx.x];
}

__global__ __launch_bounds__(256) void copy_int(const int* __restrict__ src,
                                                int* __restrict__ dst, int n) {
  int i = blockIdx.x * 256 + threadIdx.x;
  if (i < n) dst[i] = src[i];
}

__global__ __launch_bounds__(256) void fill_csr(const int* __restrict__ es,
    const int* __restrict__ ed, int* __restrict__ cursor, int* __restrict__ col, int E) {
  int i = blockIdx.x * 256 + threadIdx.x;
  if (i < E) {
    int pos = atomicAdd(&cursor[ed[i]], 1);
    col[pos] = es[i];
  }
}

// wout(bf16) = W[o0] + W[o1] (+ W[o2]); bout(f32) similarly; offsets in elements
__global__ __launch_bounds__(256) void wsum_kernel(
    const void* __restrict__ W, int o0, int o1, int o2,
    const void* __restrict__ B, int p0, int p1, int p2,
    const int* __restrict__ flagp, __hip_bfloat16* __restrict__ wout,
    float* __restrict__ bout, int wsz) {
  const bool bf = (*flagp != 0);
  int i = blockIdx.x * 256 + threadIdx.x;
  float s = 0.0f, sb = 0.0f;
  if (bf) {
    const __hip_bfloat16* Wp = (const __hip_bfloat16*)W;
    const __hip_bfloat16* Bp = (const __hip_bfloat16*)B;
    if (i < wsz) {
      s = __bfloat162float(Wp[o0 + i]) + __bfloat162float(Wp[o1 + i]);
      if (o2 >= 0) s += __bfloat162float(Wp[o2 + i]);
    }
    if (i < 64) {
      sb = __bfloat162float(Bp[p0 + i]) + __bfloat162float(Bp[p1 + i]);
      if (p2 >= 0) sb += __bfloat162float(Bp[p2 + i]);
    }
  } else {
    const float* Wp = (const float*)W;
    const float* Bp = (const float*)B;
    if (i < wsz) {
      s = Wp[o0 + i] + Wp[o1 + i];
      if (o2 >= 0) s += Wp[o2 + i];
    }
    if (i < 64) {
      sb = Bp[p0 + i] + Bp[p1 + i];
      if (p2 >= 0) sb += Bp[p2 + i];
    }
  }
  if (i < wsz) wout[i] = __float2bfloat16(s);
  if (i < 64) bout[i] = sb;
}

extern "C" void kernel_launch(void* const* d_in, const int* in_sizes, int n_in,
                              void* d_out, int out_size, void* d_ws, size_t ws_size,
                              hipStream_t stream) {
  const int NC = 100000, NM = 50000, ND = 25000;
  const int nn[3] = {NC, NM, ND};
  const size_t toff[3] = {0, (size_t)NC * 64, (size_t)(NC + NM) * 64};
  const void* X[3] = {d_in[0], d_in[1], d_in[2]};
  const int* eptr[8]; int E[8];
  for (int r = 0; r < 8; ++r) { eptr[r] = (const int*)d_in[3 + r]; E[r] = in_sizes[3 + r] / 2; }
  const void* Wls[3] = {d_in[11], d_in[14], d_in[17]};
  const void* Wrs[3] = {d_in[12], d_in[15], d_in[18]};
  const void* Bbs[3] = {d_in[13], d_in[16], d_in[19]};

  // relation r: 0:c->m 1:m->d 2:c->d 3:m->c 4:d->m 5:d->c 6:c->c 7:m->m
  const int src_t[8] = {0, 1, 0, 1, 2, 2, 0, 1};
  const int dst_t[8] = {1, 2, 2, 0, 1, 0, 0, 1};
  // relations per dst type (3rd used only in layer 3 for T=0,1)
  const int relT[3][3] = {{3, 5, 6}, {0, 4, 7}, {1, 2, -1}};

  int coff[8]; int cntN = 0;
  for (int r = 0; r < 8; ++r) { coff[r] = cntN; cntN += nn[dst_t[r]]; }
  int Etot = 0; for (int r = 0; r < 8; ++r) Etot += E[r];

  // ---- workspace carve (~60 MB; round-5 proved ws_size >= ~73 MB) ----
  // Round-6 (kept): every carve 128B-aligned -- y/h2 128B rows must not span two
  // cache lines (was a 2x L2-miss-path multiplier; FETCH 143->79 MB).
  char* base = (char*)d_ws;
  auto carve = [&](size_t bytes) -> char* {
    char* p = (char*)(((uintptr_t)base + 127) & ~(uintptr_t)127);
    base = p + bytes;
    return p;
  };
  int* flag = (int*)carve(16);
  __hip_bfloat16* wr[3];
  for (int t = 0; t < 3; ++t) wr[t] = (__hip_bfloat16*)carve(64 * 128 * 2);
  float* bs[3]; for (int t = 0; t < 3; ++t) bs[t] = (float*)carve(64 * 4);
  __hip_bfloat16* y = (__hip_bfloat16*)carve((size_t)175000 * 64 * 2);  // max rows/phase
  int* degcur = (int*)carve((size_t)cntN * 4);
  int* rowptr = (int*)carve((size_t)(cntN + 1) * 4);
  int* part = (int*)carve((size_t)(DIV_UP(cntN, 256) + 1) * 4);
  int* col = (int*)carve((size_t)Etot * 4);
  __hip_bfloat16* h2 = (__hip_bfloat16*)carve((size_t)175000 * 64 * 2);
  __hip_bfloat16* h1 = (__hip_bfloat16*)d_out;  // prefix of d_out; dead before layer-3 writes
  (void)n_in; (void)out_size; (void)ws_size;

  detect_dtype<<<1, 256, 0, stream>>>((const unsigned int*)d_in[0], flag);

  // ---- CSR build (edges fixed; shared by all layers) ----
  hipMemsetAsync(degcur, 0, (size_t)cntN * sizeof(int), stream);
  for (int r = 0; r < 8; ++r)
    count_int<<<DIV_UP(E[r], 256), 256, 0, stream>>>(eptr[r] + E[r], degcur + coff[r], E[r]);
  int nb = DIV_UP(cntN, 256);
  scan1<<<nb, 256, 0, stream>>>(degcur, rowptr, part, cntN);
  scan2<<<1, 256, 0, stream>>>(part, nb, rowptr + cntN);
  scan3<<<nb, 256, 0, stream>>>(rowptr, part, cntN);
  copy_int<<<nb, 256, 0, stream>>>(rowptr, degcur, cntN);  // degcur -> cursor
  for (int r = 0; r < 8; ++r)
    fill_csr<<<DIV_UP(E[r], 256), 256, 0, stream>>>(eptr[r], eptr[r] + E[r],
                                                    degcur + coff[r], col, E[r]);

  for (int layer = 0; layer < 3; ++layer) {
    const void* Wl = Wls[layer];
    const void* Wr = Wrs[layer];
    const void* Bb = Bbs[layer];
    const int K = (layer == 0) ? 128 : 64;
    const int wsz = 64 * K;
    const __hip_bfloat16* hin = (layer == 1) ? h1 : h2;  // layer 0 uses X

    for (int T = 0; T < 3; ++T) {
      const int nrel = (layer == 2 && T < 2) ? 3 : 2;
      const int r0 = relT[T][0], r1 = relT[T][1];
      const int r2 = (nrel == 3) ? relT[T][2] : -1;
      wsum_kernel<<<DIV_UP(wsz, 256), 256, 0, stream>>>(
          Wr, r0 * wsz, r1 * wsz, (r2 >= 0) ? r2 * wsz : -1,
          Bb, r0 * 64, r1 * 64, (r2 >= 0) ? r2 * 64 : -1,
          flag, wr[T], bs[T], wsz);
      // y GEMMs for this dst type's relations
      size_t yoffs[3] = {0, 0, 0};
      size_t yoff = 0;
      for (int j = 0; j < nrel; ++j) {
        int r = relT[T][j], st = src_t[r];
        yoffs[j] = yoff;
        if (layer == 0)
          gemm_mfma<128><<<DIV_UP(nn[st], 64), 256, 0, stream>>>(
              X[st], 2, Wl, r * wsz, 2, flag, y + yoff, nn[st]);
        else
          gemm_mfma<64><<<DIV_UP(nn[st], 64), 256, 0, stream>>>(
              hin + toff[st], 1, Wl, r * wsz, 2, flag, y + yoff, nn[st]);
        yoff += (size_t)nn[st] * 64;
      }
      // fused lin_r + gather + epilogue
      const int* rp0 = rowptr + coff[r0];
      const int* rp1 = rowptr + coff[r1];
      const int* rp2 = (r2 >= 0) ? rowptr + coff[r2] : rp0;
      const __hip_bfloat16* y0 = y + yoffs[0];
      const __hip_bfloat16* y1 = y + yoffs[1];
      const __hip_bfloat16* y2 = (r2 >= 0) ? y + yoffs[2] : y0;
      int grid = DIV_UP(nn[T], 16);
      if (layer == 0) {
        fused_agg<128, 0, 2><<<grid, 256, 0, stream>>>(
            X[T], 2, flag, wr[T], bs[T], col, rp0, y0, rp1, y1, rp2, y2,
            0.5f, h1, toff[T], nn[T]);
      } else if (layer == 1) {
        fused_agg<64, 0, 2><<<grid, 256, 0, stream>>>(
            h1 + toff[T], 1, flag, wr[T], bs[T], col, rp0, y0, rp1, y1, rp2, y2,
            0.5f, h2, toff[T], nn[T]);
      } else if (T < 2) {
        fused_agg<64, 1, 3><<<grid, 256, 0, stream>>>(
            h2 + toff[T], 1, flag, wr[T], bs[T], col, rp0, y0, rp1, y1, rp2, y2,
            1.0f / 3.0f, d_out, toff[T], nn[T]);
      } else {
        fused_agg<64, 1, 2><<<grid, 256, 0, stream>>>(
            h2 + toff[T], 1, flag, wr[T], bs[T], col, rp0, y0, rp1, y1, rp2, y2,
            0.5f, d_out, toff[T], nn[T]);
      }
    }
  }
}